// Round 4
// baseline (432.745 us; speedup 1.0000x reference)
//
#include <hip/hip_runtime.h>
#include <hip/hip_bf16.h>
#include <math.h>

// Problem constants
#define BB 2
#define SS 2048
#define DDIM 1024
#define NHEAD 16
#define NSTR 8
#define SDIMC 128
#define NCH 16      // chunks for delta scan
#define CLEN 128    // chunk length
#define EPSV 1e-6f

using bf16 = __hip_bfloat16;
typedef __attribute__((ext_vector_type(8))) __bf16 bf8;
typedef __attribute__((ext_vector_type(4))) __bf16 bf4v;
typedef __attribute__((ext_vector_type(4))) float f4;

__device__ __forceinline__ bf16 f2b(float v) { return __float2bfloat16(v); }
__device__ __forceinline__ bf8 ld8(const bf16* p) { return *(const bf8*)p; }
__device__ __forceinline__ f4 MFMA(bf8 a, bf8 b, f4 c) {
  return __builtin_amdgcn_mfma_f32_16x16x32_bf16(a, b, c, 0, 0, 0);
}
__device__ __forceinline__ float sigm(float x) { return 1.0f / (1.0f + expf(-x)); }
__device__ __forceinline__ float fexp2(float x) { return __builtin_amdgcn_exp2f(x); }

// fast gelu (exact-erf form) via Abramowitz-Stegun 7.1.26: |erf err| <= 1.5e-7,
// far below bf16 store rounding. hw rcp + hw exp2 instead of libm erff.
__device__ __forceinline__ float gelu_f(float v) {
  float x = v * 0.70710678118654752f;
  float ax = fabsf(x);
  float t = __builtin_amdgcn_rcpf(1.0f + 0.3275911f * ax);
  float p = ((((1.061405429f * t - 1.453152027f) * t + 1.421413741f) * t
              - 0.284496736f) * t + 0.254829592f) * t;
  float e = 1.0f - p * fexp2(-ax * ax * 1.4426950408889634f);
  e = copysignf(e, x);
  return 0.5f * v * (1.0f + e);
}

// async global->LDS 16B copy (m97 pattern; LDS dest must be uniform + lane*16)
__device__ __forceinline__ void glds16(bf16* l, const bf16* g) {
  __builtin_amdgcn_global_load_lds(
      (const __attribute__((address_space(1))) unsigned int*)g,
      (__attribute__((address_space(3))) unsigned int*)l, 16, 0, 0);
}

// ---------------- f32 -> bf16 weight conversion (all 4 weights, one launch) --
__global__ __launch_bounds__(256) void cvt_all(const float* __restrict__ ipw,
                                               const float* __restrict__ ow,
                                               const float* __restrict__ w1,
                                               const float* __restrict__ w2,
                                               bf16* __restrict__ WIPW,
                                               bf16* __restrict__ WOW,
                                               bf16* __restrict__ W1B,
                                               bf16* __restrict__ W2B) {
  const int S1 = 3 * DDIM * DDIM, S2 = S1 + DDIM * DDIM,
            S3 = S2 + 4 * DDIM * DDIM;
  int i4 = (blockIdx.x * 256 + threadIdx.x) * 4;   // grid covers 12.58M elems
  const float* src;
  bf16* dst;
  int off;
  if (i4 < S1)      { src = ipw; dst = WIPW; off = i4; }
  else if (i4 < S2) { src = ow;  dst = WOW;  off = i4 - S1; }
  else if (i4 < S3) { src = w1;  dst = W1B;  off = i4 - S2; }
  else              { src = w2;  dst = W2B;  off = i4 - S3; }
  float4 v = *(const float4*)(src + off);
  bf4v o;
  o[0] = (__bf16)v.x; o[1] = (__bf16)v.y; o[2] = (__bf16)v.z; o[3] = (__bf16)v.w;
  *(bf4v*)(dst + off) = o;                         // one 8B store, fully packed
}

// ---------------- Delta operator: 3-pass chunked affine scan ----------------
__global__ __launch_bounds__(256) void delta_passA(const float* __restrict__ x,
                                                   const float* __restrict__ decay,
                                                   float* __restrict__ SA) {
  int idx = blockIdx.x * 256 + threadIdx.x;      // [b][c][d]
  int d = idx % DDIM;
  int c = (idx / DDIM) % NCH;
  int b = idx / (DDIM * NCH);
  float beta = sigm(decay[d]);
  float omb = 1.0f - beta;
  const float* xp = x + ((size_t)(b * SS + c * CLEN)) * DDIM + d;
  float s = 0.0f;
  for (int j = 0; j < CLEN; j++) {
    float xv = xp[(size_t)j * DDIM];
    s = beta * s + omb * xv;
  }
  SA[idx] = s;
}

__global__ __launch_bounds__(256) void delta_passB(const float* __restrict__ SA,
                                                   const float* __restrict__ decay,
                                                   float* __restrict__ SIN) {
  int idx = blockIdx.x * 256 + threadIdx.x;      // [b][d]
  int d = idx % DDIM;
  int b = idx / DDIM;
  float beta = sigm(decay[d]);
  float p = beta;
  for (int i = 0; i < 7; i++) p *= p;            // beta^128
  float s = 0.0f;
  for (int c = 0; c < NCH; c++) {
    SIN[(b * NCH + c) * DDIM + d] = s;
    s = p * s + SA[(b * NCH + c) * DDIM + d];
  }
}

__global__ __launch_bounds__(256) void delta_passC(const float* __restrict__ x,
                                                   const float* __restrict__ decay,
                                                   const float* __restrict__ SIN,
                                                   float* __restrict__ XD,
                                                   float* __restrict__ SA) {
  int idx = blockIdx.x * 256 + threadIdx.x;      // [b][c][d]
  int d = idx % DDIM;
  int c = (idx / DDIM) % NCH;
  int b = idx / (DDIM * NCH);
  float beta = sigm(decay[d]);
  float omb = 1.0f - beta;
  const float* xp = x + ((size_t)(b * SS + c * CLEN)) * DDIM + d;
  float* xdp = XD + ((size_t)(b * SS + c * CLEN)) * DDIM + d;
  float s = SIN[idx];
  float sum = 0.0f;
  for (int j = 0; j < CLEN; j++) {
    float xv = xp[(size_t)j * DDIM];
    float o = xv - s;
    xdp[(size_t)j * DDIM] = o;
    sum += o;
    s = beta * s + omb * xv;
  }
  SA[idx] = sum;
}

// ---------------- gates (g_res) + sinkhorn ----------------
__global__ __launch_bounds__(1024) void gates_sinkhorn(const float* __restrict__ SA,
                                                       const float* __restrict__ gw,
                                                       const float* __restrict__ gb,
                                                       const float* __restrict__ phi,
                                                       float* __restrict__ gres,
                                                       float* __restrict__ hres) {
  int tid = threadIdx.x;
  int wave = tid >> 6, lane = tid & 63;
  int b = wave >> 3, j = wave & 7;               // 16 waves: (b, gate j)
  float acc = 0.0f;
  for (int d = lane; d < DDIM; d += 64) {
    float xs = 0.0f;
    for (int c = 0; c < NCH; c++) xs += SA[(b * NCH + c) * DDIM + d];
    xs *= (1.0f / (float)SS);
    acc += xs * gw[(2 * NSTR + j) * DDIM + d];
  }
  for (int off = 32; off > 0; off >>= 1) acc += __shfl_down(acc, off);
  if (lane == 0) gres[b * NSTR + j] = sigm(acc + gb[2 * NSTR + j]);
  __syncthreads();
  if (tid == 0) {
    float Km[8][8];
    for (int i = 0; i < 8; i++)
      for (int jj = 0; jj < 8; jj++) Km[i][jj] = expf(phi[i * 8 + jj]);
    for (int it = 0; it < 15; it++) {
      for (int i = 0; i < 8; i++) {
        float rs = 0.0f;
        for (int jj = 0; jj < 8; jj++) rs += Km[i][jj];
        float inv = 1.0f / rs;
        for (int jj = 0; jj < 8; jj++) Km[i][jj] *= inv;
      }
      for (int jj = 0; jj < 8; jj++) {
        float cs = 0.0f;
        for (int i = 0; i < 8; i++) cs += Km[i][jj];
        float inv = 1.0f / cs;
        for (int i = 0; i < 8; i++) Km[i][jj] *= inv;
      }
    }
    for (int i = 0; i < 8; i++)
      for (int jj = 0; jj < 8; jj++) hres[i * 8 + jj] = Km[i][jj];
  }
}

// ---------------- RMSNorm (f32 in -> bf16 out) ----------------
__global__ __launch_bounds__(256) void rmsnorm_k(const float* __restrict__ in,
                                                 const float* __restrict__ w,
                                                 bf16* __restrict__ out) {
  int row = blockIdx.x;
  const float* r = in + (size_t)row * DDIM;
  int tid = threadIdx.x;
  float ss = 0.0f;
  for (int i = tid; i < DDIM; i += 256) {
    float v = r[i];
    ss += v * v;
  }
  for (int off = 32; off > 0; off >>= 1) ss += __shfl_down(ss, off);
  __shared__ float red[4];
  if ((tid & 63) == 0) red[tid >> 6] = ss;
  __syncthreads();
  float tot = red[0] + red[1] + red[2] + red[3];
  float sc = rsqrtf(tot / (float)DDIM + EPSV);
  bf16* o = out + (size_t)row * DDIM;
  for (int i = tid; i < DDIM; i += 256) o[i] = f2b(r[i] * sc * w[i]);
}

// ------- MFMA GEMM, 128x128 tile, BK=32, TRIPLE-BUFFERED counted-vmcnt loop.
// T4: tile t+2 prefetched at iter t; end-of-iter wait is s_waitcnt vmcnt(4)
// (tile t+1's 4 loads -- issued a full iteration ago -- must land; tile t+2's
// 4 stay in flight) + RAW s_barrier. Never vmcnt(0) in steady state.
// Safety: the end barrier separates reads of buf[t%3] from iter t+1's stage
// into that same buffer; vmcnt is FIFO so stray compiler loads only make the
// wait conservative.
// ODT: 0=f32 out, 1=bf16 out.  EPI: 0=none, 1=gelu(exact erf), 2=add residual
template <int ODT, int EPI>
__global__ __launch_bounds__(256) void gemm_lds(const bf16* __restrict__ A,
                                                const bf16* __restrict__ W,
                                                const float* __restrict__ bias,
                                                const float* __restrict__ res,
                                                void* __restrict__ outp,
                                                int M, int N, int K) {
  __shared__ bf16 As[3][128 * 32];
  __shared__ bf16 Bs[3][128 * 32];
  int tid = threadIdx.x;
  int lane = tid & 63, wv = tid >> 6;
  int ml = lane & 15, quad = lane >> 4;
  int wr = wv >> 1, wc = wv & 1;
  int m0 = blockIdx.x * 128, n0 = blockIdx.y * 128;
  // per-thread staging addresses (2 chunks each of A,B)
  const bf16* ga[2];
  const bf16* gb[2];
  int lofs[2];
#pragma unroll
  for (int it = 0; it < 2; it++) {
    int c = it * 256 + tid;             // 512 16B-chunks per tile
    int row = c >> 2, kc = (c & 3) * 8;
    ga[it] = A + (size_t)(m0 + row) * K + kc;
    gb[it] = W + (size_t)(n0 + row) * K + kc;
    lofs[it] = c * 8;
  }
  // prologue: stage tiles 0 and 1 (nk >= 2 always here)
#pragma unroll
  for (int it = 0; it < 2; it++) {
    glds16(&As[0][lofs[it]], ga[it]);
    glds16(&Bs[0][lofs[it]], gb[it]);
  }
#pragma unroll
  for (int it = 0; it < 2; it++) {
    glds16(&As[1][lofs[it]], ga[it] + 32);
    glds16(&Bs[1][lofs[it]], gb[it] + 32);
  }
  f4 acc[4][4] = {};
  int nk = K >> 5;
  asm volatile("s_waitcnt vmcnt(4)" ::: "memory");   // tile 0 landed
  __builtin_amdgcn_s_barrier();
  int cur = 0;
  for (int t = 0; t < nk; t++) {
    if (t + 2 < nk) {                    // prefetch tile t+2 (depth-2)
      int ko = (t + 2) * 32;
      int nb = cur + 2; if (nb >= 3) nb -= 3;
#pragma unroll
      for (int it = 0; it < 2; it++) {
        glds16(&As[nb][lofs[it]], ga[it] + ko);
        glds16(&Bs[nb][lofs[it]], gb[it] + ko);
      }
    }
    bf8 af[4], bfr[4];
#pragma unroll
    for (int mi = 0; mi < 4; mi++)
      af[mi] = ld8(&As[cur][(wr * 64 + mi * 16 + ml) * 32 + quad * 8]);
#pragma unroll
    for (int ni = 0; ni < 4; ni++)
      bfr[ni] = ld8(&Bs[cur][(wc * 64 + ni * 16 + ml) * 32 + quad * 8]);
#pragma unroll
    for (int mi = 0; mi < 4; mi++)
#pragma unroll
      for (int ni = 0; ni < 4; ni++)
        acc[mi][ni] = MFMA(af[mi], bfr[ni], acc[mi][ni]);
    if (t + 2 < nk) {                    // tile t+1 ready; t+2 stays in flight
      asm volatile("s_waitcnt vmcnt(4)" ::: "memory");
      __builtin_amdgcn_s_barrier();
    } else if (t + 1 < nk) {             // tail: only tile t+1 outstanding
      asm volatile("s_waitcnt vmcnt(0)" ::: "memory");
      __builtin_amdgcn_s_barrier();
    }
    cur++; if (cur >= 3) cur = 0;
  }
#pragma unroll
  for (int mi = 0; mi < 4; mi++)
#pragma unroll
    for (int ni = 0; ni < 4; ni++)
#pragma unroll
      for (int r = 0; r < 4; r++) {
        int row = m0 + wr * 64 + mi * 16 + quad * 4 + r;
        int col = n0 + wc * 64 + ni * 16 + ml;
        size_t idx = (size_t)row * N + col;
        float v = acc[mi][ni][r] + bias[col];
        if (EPI == 1) v = gelu_f(v);
        if (EPI == 2) v += res[idx];
        if (ODT == 1) ((bf16*)outp)[idx] = f2b(v);
        else ((float*)outp)[idx] = v;
      }
}

// ------- ffn2 split-K=2, ONE launch, grid (32,8,2): z picks K-slice+buffer ---
// same triple-buffered counted-vmcnt structure
__global__ __launch_bounds__(256) void gemm_part2(const bf16* __restrict__ A,
                                                  const bf16* __restrict__ W,
                                                  float* __restrict__ P0,
                                                  float* __restrict__ P1,
                                                  int M, int N, int KS, int LDK) {
  __shared__ bf16 As[3][128 * 32];
  __shared__ bf16 Bs[3][128 * 32];
  int tid = threadIdx.x;
  int lane = tid & 63, wv = tid >> 6;
  int ml = lane & 15, quad = lane >> 4;
  int wr = wv >> 1, wc = wv & 1;
  int m0 = blockIdx.x * 128, n0 = blockIdx.y * 128;
  const bf16* Ab = A + blockIdx.z * KS;
  const bf16* Wb = W + blockIdx.z * KS;
  float* P = blockIdx.z ? P1 : P0;
  const bf16* ga[2];
  const bf16* gb[2];
  int lofs[2];
#pragma unroll
  for (int it = 0; it < 2; it++) {
    int c = it * 256 + tid;
    int row = c >> 2, kc = (c & 3) * 8;
    ga[it] = Ab + (size_t)(m0 + row) * LDK + kc;
    gb[it] = Wb + (size_t)(n0 + row) * LDK + kc;
    lofs[it] = c * 8;
  }
#pragma unroll
  for (int it = 0; it < 2; it++) {
    glds16(&As[0][lofs[it]], ga[it]);
    glds16(&Bs[0][lofs[it]], gb[it]);
  }
#pragma unroll
  for (int it = 0; it < 2; it++) {
    glds16(&As[1][lofs[it]], ga[it] + 32);
    glds16(&Bs[1][lofs[it]], gb[it] + 32);
  }
  f4 acc[4][4] = {};
  int nk = KS >> 5;
  asm volatile("s_waitcnt vmcnt(4)" ::: "memory");
  __builtin_amdgcn_s_barrier();
  int cur = 0;
  for (int t = 0; t < nk; t++) {
    if (t + 2 < nk) {
      int ko = (t + 2) * 32;
      int nb = cur + 2; if (nb >= 3) nb -= 3;
#pragma unroll
      for (int it = 0; it < 2; it++) {
        glds16(&As[nb][lofs[it]], ga[it] + ko);
        glds16(&Bs[nb][lofs[it]], gb[it] + ko);
      }
    }
    bf8 af[4], bfr[4];
#pragma unroll
    for (int mi = 0; mi < 4; mi++)
      af[mi] = ld8(&As[cur][(wr * 64 + mi * 16 + ml) * 32 + quad * 8]);
#pragma unroll
    for (int ni = 0; ni < 4; ni++)
      bfr[ni] = ld8(&Bs[cur][(wc * 64 + ni * 16 + ml) * 32 + quad * 8]);
#pragma unroll
    for (int mi = 0; mi < 4; mi++)
#pragma unroll
      for (int ni = 0; ni < 4; ni++)
        acc[mi][ni] = MFMA(af[mi], bfr[ni], acc[mi][ni]);
    if (t + 2 < nk) {
      asm volatile("s_waitcnt vmcnt(4)" ::: "memory");
      __builtin_amdgcn_s_barrier();
    } else if (t + 1 < nk) {
      asm volatile("s_waitcnt vmcnt(0)" ::: "memory");
      __builtin_amdgcn_s_barrier();
    }
    cur++; if (cur >= 3) cur = 0;
  }
#pragma unroll
  for (int mi = 0; mi < 4; mi++)
#pragma unroll
    for (int ni = 0; ni < 4; ni++)
#pragma unroll
      for (int r = 0; r < 4; r++) {
        int row = m0 + wr * 64 + mi * 16 + quad * 4 + r;
        int col = n0 + wc * 64 + ni * 16 + ml;
        P[(size_t)row * N + col] = acc[mi][ni][r];
      }
}

// ------- MFMA GEMM, BM=64 x BN=128 variant, triple-buffered counted-vmcnt ---
// 3 staging ops/tile/thread (1 A + 2 B) -> steady-state wait is vmcnt(3)
template <int ODT, int EPI>
__global__ __launch_bounds__(256) void gemm_lds64(const bf16* __restrict__ A,
                                                  const bf16* __restrict__ W,
                                                  const float* __restrict__ bias,
                                                  const float* __restrict__ res,
                                                  void* __restrict__ outp,
                                                  int M, int N, int K) {
  __shared__ bf16 As[3][64 * 32];
  __shared__ bf16 Bs[3][128 * 32];
  int tid = threadIdx.x;
  int lane = tid & 63, wv = tid >> 6;
  int ml = lane & 15, quad = lane >> 4;
  int wr = wv & 1, wc = wv >> 1;        // wave tile: 32 rows x 64 cols
  int m0 = blockIdx.x * 64, n0 = blockIdx.y * 128;
  const bf16* gaA;
  const bf16* gb[2];
  int lofA, lofs[2];
  {
    int c = tid;                        // A: 256 chunks
    int row = c >> 2, kc = (c & 3) * 8;
    gaA = A + (size_t)(m0 + row) * K + kc;
    lofA = c * 8;
  }
#pragma unroll
  for (int it = 0; it < 2; it++) {      // B: 512 chunks
    int c = it * 256 + tid;
    int row = c >> 2, kc = (c & 3) * 8;
    gb[it] = W + (size_t)(n0 + row) * K + kc;
    lofs[it] = c * 8;
  }
  glds16(&As[0][lofA], gaA);
#pragma unroll
  for (int it = 0; it < 2; it++) glds16(&Bs[0][lofs[it]], gb[it]);
  glds16(&As[1][lofA], gaA + 32);
#pragma unroll
  for (int it = 0; it < 2; it++) glds16(&Bs[1][lofs[it]], gb[it] + 32);
  f4 acc[2][4] = {};
  int nk = K >> 5;
  asm volatile("s_waitcnt vmcnt(3)" ::: "memory");   // tile 0 landed
  __builtin_amdgcn_s_barrier();
  int cur = 0;
  for (int t = 0; t < nk; t++) {
    if (t + 2 < nk) {
      int ko = (t + 2) * 32;
      int nb = cur + 2; if (nb >= 3) nb -= 3;
      glds16(&As[nb][lofA], gaA + ko);
#pragma unroll
      for (int it = 0; it < 2; it++) glds16(&Bs[nb][lofs[it]], gb[it] + ko);
    }
    bf8 af[2], bfr[4];
#pragma unroll
    for (int mi = 0; mi < 2; mi++)
      af[mi] = ld8(&As[cur][(wr * 32 + mi * 16 + ml) * 32 + quad * 8]);
#pragma unroll
    for (int ni = 0; ni < 4; ni++)
      bfr[ni] = ld8(&Bs[cur][(wc * 64 + ni * 16 + ml) * 32 + quad * 8]);
#pragma unroll
    for (int mi = 0; mi < 2; mi++)
#pragma unroll
      for (int ni = 0; ni < 4; ni++)
        acc[mi][ni] = MFMA(af[mi], bfr[ni], acc[mi][ni]);
    if (t + 2 < nk) {
      asm volatile("s_waitcnt vmcnt(3)" ::: "memory");
      __builtin_amdgcn_s_barrier();
    } else if (t + 1 < nk) {
      asm volatile("s_waitcnt vmcnt(0)" ::: "memory");
      __builtin_amdgcn_s_barrier();
    }
    cur++; if (cur >= 3) cur = 0;
  }
#pragma unroll
  for (int mi = 0; mi < 2; mi++)
#pragma unroll
    for (int ni = 0; ni < 4; ni++)
#pragma unroll
      for (int r = 0; r < 4; r++) {
        int row = m0 + wr * 32 + mi * 16 + quad * 4 + r;
        int col = n0 + wc * 64 + ni * 16 + ml;
        size_t idx = (size_t)row * N + col;
        float v = acc[mi][ni][r] + bias[col];
        if (EPI == 1) v = gelu_f(v);
        if (EPI == 2) v += res[idx];
        if (ODT == 1) ((bf16*)outp)[idx] = f2b(v);
        else ((float*)outp)[idx] = v;
      }
}

// ---------------- V transpose: VT[b,h,d,s] = qkv[b,s,2D + h*64 + d] --------
__global__ __launch_bounds__(256) void vtrans(const bf16* __restrict__ qkv,
                                              bf16* __restrict__ VT) {
  int bid = blockIdx.x;
  int st = bid % (SS / 64);
  int h = (bid / (SS / 64)) % NHEAD;
  int b = bid / ((SS / 64) * NHEAD);
  __shared__ bf16 tile[64][65];
  int s0 = st * 64;
  int tid = threadIdx.x;
  for (int it = 0; it < 16; it++) {
    int sl = it * 4 + (tid >> 6), dl = tid & 63;
    tile[sl][dl] = qkv[(size_t)(b * SS + s0 + sl) * (3 * DDIM) + 2 * DDIM + h * 64 + dl];
  }
  __syncthreads();
  for (int it = 0; it < 16; it++) {
    int dl = it * 4 + (tid >> 6), sl = tid & 63;
    VT[((size_t)(b * NHEAD + h) * 64 + dl) * SS + s0 + sl] = tile[sl][dl];
  }
}

// ---- Flash attention v10: SWAPPED QK^T (mfma(K,Q) -> S^T, lane owns one
// q-row) -> in-lane softmax: 8 shuffles/phase (was 32), packed b64 P-writes
// (was 16 scalar), K/V fragments loaded ONCE per tile shared by both
// antithetic phases. Same fragment loads serve as A resp. B operands.
// C-layout of swapped QK^T: q = ml, k = k0 + c*16 + quad*4 + r.
// O-layout (PV unchanged): q = q0 + quad*4 + r, d = c*16 + ml -> alpha/l
// redistributed via 4 shuffles (lane quad*4+r holds q-row quad*4+r's state).
__device__ __forceinline__ void qk_softmax(bool active, int kt, int q0, int nkt,
                                           const bf8 kf[4][2], const bf8* qf,
                                           f4* oacc, float& m, float& l,
                                           bf8* pf, bf16 (*pl)[72],
                                           int ml, int quad, int k0) {
  if (!active) return;                   // block-uniform condition
  const float SC = 0.125f * 1.44269504089f;  // 1/sqrt(64) * log2(e)
  f4 s[4] = {{0,0,0,0},{0,0,0,0},{0,0,0,0},{0,0,0,0}};
  __builtin_amdgcn_s_setprio(1);
#pragma unroll
  for (int kk = 0; kk < 2; kk++)
#pragma unroll
    for (int c = 0; c < 4; c++)
      s[c] = MFMA(kf[c][kk], qf[kk], s[c]);   // S^T = K . Q^T
  __builtin_amdgcn_s_setprio(0);
  if (kt == nkt - 1) {                   // diagonal tile: causal mask
    int qi = q0 + ml;
#pragma unroll
    for (int c = 0; c < 4; c++)
#pragma unroll
      for (int r = 0; r < 4; r++)
        if (k0 + c * 16 + quad * 4 + r > qi) s[c][r] = -1e30f;
  }
  // in-lane max over 16 k-values, then 2-step quad reduce
  float mx = s[0][0];
#pragma unroll
  for (int c = 0; c < 4; c++)
#pragma unroll
    for (int r = 0; r < 4; r++) mx = fmaxf(mx, s[c][r]);
  mx = fmaxf(mx, __shfl_xor(mx, 16));
  mx = fmaxf(mx, __shfl_xor(mx, 32));
  float mn = fmaxf(m, mx * SC);
  float alpha = fexp2(m - mn);
  float rs = 0.0f;
  float p[4][4];
#pragma unroll
  for (int c = 0; c < 4; c++)
#pragma unroll
    for (int r = 0; r < 4; r++) {
      p[c][r] = fexp2(__builtin_fmaf(s[c][r], SC, -mn));
      rs += p[c][r];
    }
  rs += __shfl_xor(rs, 16);
  rs += __shfl_xor(rs, 32);
  l = l * alpha + rs;
  m = mn;
  // redistribute alpha (state row q=ml) to O-layout rows (q=quad*4+r):
  // source lane quad*4+r (lanes 0..15) holds q-row quad*4+r's alpha
  float alr[4];
#pragma unroll
  for (int r = 0; r < 4; r++) alr[r] = __shfl(alpha, quad * 4 + r);
#pragma unroll
  for (int c = 0; c < 4; c++)
#pragma unroll
    for (int r = 0; r < 4; r++) oacc[c][r] *= alr[r];
  // P is lane-local: pack 4 bf16 per chunk, one b64 write each (2-way banks)
#pragma unroll
  for (int c = 0; c < 4; c++) {
    bf4v w;
#pragma unroll
    for (int r = 0; r < 4; r++) w[r] = (__bf16)p[c][r];
    *(bf4v*)&pl[ml][c * 16 + quad * 4] = w;
  }
#pragma unroll
  for (int kk = 0; kk < 2; kk++) pf[kk] = ld8(&pl[ml][kk * 32 + quad * 8]);
}

__device__ __forceinline__ void pv_acc(bool active, const bf8* pf,
                                       const bf8 vf[4][2], f4* oacc) {
  if (!active) return;
  __builtin_amdgcn_s_setprio(1);
#pragma unroll
  for (int c = 0; c < 4; c++)
#pragma unroll
    for (int kk = 0; kk < 2; kk++)
      oacc[c] = MFMA(pf[kk], vf[c][kk], oacc[c]);
  __builtin_amdgcn_s_setprio(0);
}

__global__ __launch_bounds__(256) void flash_attn(const bf16* __restrict__ qkv,
                                                  const bf16* __restrict__ VT,
                                                  bf16* __restrict__ obuf) {
  // T1 XCD swizzle: 512 blocks, 8 XCDs, dispatch round-robins rb%8. Remap so
  // XCD x handles logical bids [x*64, x*64+64) = 4 complete (b,h) groups ->
  // that XCD's L2 holds their K/V (4 x 512KB = 2MB < 4MB). Bijective.
  int rb = blockIdx.x;
  int bid = (rb & 7) * 64 + (rb >> 3);
  // complementary blk pairing: adjacent logical blocks get workloads summing
  // to a constant 49 tiles (maxn(blk)=32-blk; pair j/2 with 15-j/2).
  int j = bid & 15;
  int blk = (j & 1) ? (15 - (j >> 1)) : (j >> 1);
  int h = (bid >> 4) & 15;
  int b = bid >> 8;
  int tid = threadIdx.x;
  int wv = tid >> 6, lane = tid & 63;
  int ml = lane & 15, quad = lane >> 4;
  int idx0 = blk * 4 + wv;              // phase-0 subtile (16 Q rows)
  int idx1 = 127 - idx0;                // phase-1 (antithetic)
  int q0a = idx0 * 16, q0b = idx1 * 16;
  int nkt0 = blk + 1;                   // block-uniform (idx0>>2 == blk)
  int nkt1 = 32 - blk;                  // block-uniform; nkt1 >= nkt0
  int maxn = nkt1;

  __shared__ __align__(16) bf16 Ks[2][64 * 64];
  __shared__ __align__(16) bf16 Vs[2][64 * 64];
  __shared__ __align__(16) bf16 plds[4][2][16][72];  // per-wave, per-phase
  bf16 (*plA)[72] = plds[wv][0];
  bf16 (*plB)[72] = plds[wv][1];

  bf8 qfa[2], qfb[2];
#pragma unroll
  for (int kk = 0; kk < 2; kk++) {
    qfa[kk] = ld8(qkv + (size_t)(b * SS + q0a + ml) * (3 * DDIM) + h * 64 + kk * 32 + quad * 8);
    qfb[kk] = ld8(qkv + (size_t)(b * SS + q0b + ml) * (3 * DDIM) + h * 64 + kk * 32 + quad * 8);
  }
  f4 oacca[4] = {{0,0,0,0},{0,0,0,0},{0,0,0,0},{0,0,0,0}};
  f4 oaccb[4] = {{0,0,0,0},{0,0,0,0},{0,0,0,0},{0,0,0,0}};
  float ma = -1e30f, la = 0.0f, mb = -1e30f, lb = 0.0f;

  const bf16* kglob = qkv + (size_t)b * SS * (3 * DDIM) + DDIM + h * 64;
  const bf16* vglob = VT + (size_t)(b * NHEAD + h) * 64 * SS;

  // prologue: stage tile 0 into buffer 0 (swizzled SOURCE, lane-linear dest)
#pragma unroll
  for (int it = 0; it < 2; it++) {
    int lam = it * 256 + tid;
    int row = lam >> 3;
    int ch = (lam & 7) ^ (row & 7);
    glds16(&Ks[0][lam * 8], kglob + (size_t)row * (3 * DDIM) + ch * 8);
    glds16(&Vs[0][lam * 8], vglob + (size_t)row * SS + ch * 8);
  }
  __syncthreads();
  int cur = 0;
  for (int kt = 0; kt < maxn; kt++) {
    int k0 = kt * 64;
    if (kt + 1 < maxn) {                // prefetch next K/V tile
      int k0n = (kt + 1) * 64;
#pragma unroll
      for (int it = 0; it < 2; it++) {
        int lam = it * 256 + tid;
        int row = lam >> 3;
        int ch = (lam & 7) ^ (row & 7);
        glds16(&Ks[cur ^ 1][lam * 8], kglob + (size_t)(k0n + row) * (3 * DDIM) + ch * 8);
        glds16(&Vs[cur ^ 1][lam * 8], vglob + (size_t)row * SS + k0n + ch * 8);
      }
    }
    bool act0 = kt < nkt0;              // block-uniform
    // K fragments: loaded once, shared by both phases (same ld8 serves as
    // MFMA A operand in swapped QK^T)
    bf8 kf[4][2];
#pragma unroll
    for (int kk = 0; kk < 2; kk++)
#pragma unroll
      for (int c = 0; c < 4; c++) {
        int chunk = ((c * 16 + ml) << 3) + ((kk * 4 + quad) ^ (ml & 7));
        kf[c][kk] = ld8(&Ks[cur][chunk * 8]);
      }
    bf8 pfa[2], pfb[2];
    qk_softmax(act0, kt, q0a, nkt0, kf, qfa, oacca, ma, la, pfa, plA, ml, quad, k0);
    qk_softmax(true, kt, q0b, nkt1, kf, qfb, oaccb, mb, lb, pfb, plB, ml, quad, k0);
    // V fragments: loaded once, shared by both phases
    bf8 vf[4][2];
#pragma unroll
    for (int kk = 0; kk < 2; kk++)
#pragma unroll
      for (int c = 0; c < 4; c++) {
        int chunk = ((c * 16 + ml) << 3) + ((kk * 4 + quad) ^ (ml & 7));
        vf[c][kk] = ld8(&Vs[cur][chunk * 8]);
      }
    pv_acc(act0, pfa, vf, oacca);
    pv_acc(true, pfb, vf, oaccb);
    __syncthreads();                    // vmcnt(0)+lgkmcnt(0)+barrier
    cur ^= 1;
  }
  // redistribute l (state row q=ml) to O-layout rows, then store
  float lna[4], lnb[4];
#pragma unroll
  for (int r = 0; r < 4; r++) {
    lna[r] = __shfl(la, quad * 4 + r);
    lnb[r] = __shfl(lb, quad * 4 + r);
  }
#pragma unroll
  for (int c = 0; c < 4; c++)
#pragma unroll
    for (int r = 0; r < 4; r++) {
      int rowa = q0a + quad * 4 + r;
      int rowb = q0b + quad * 4 + r;
      obuf[(size_t)(b * SS + rowa) * DDIM + h * 64 + c * 16 + ml] =
          f2b(oacca[c][r] / lna[r]);
      obuf[(size_t)(b * SS + rowb) * DDIM + h * 64 + c * 16 + ml] =
          f2b(oaccb[c][r] / lnb[r]);
    }
}

// ---------------- final: out = y + P0 + P1 + b2 + mhc(XD) ----------------
__global__ __launch_bounds__(256) void final_k(const float* __restrict__ y,
                                               const float* __restrict__ P0,
                                               const float* __restrict__ P1,
                                               const float* __restrict__ bias,
                                               const float* __restrict__ xd,
                                               const float* __restrict__ hres,
                                               const float* __restrict__ gres,
                                               float* __restrict__ out) {
  int row = blockIdx.x;  // [B*S]
  int b = row / SS;
  int tid = threadIdx.x;
  __shared__ float cf[8][8];
  if (tid < 64) cf[tid >> 3][tid & 7] = hres[tid] * gres[b * NSTR + (tid & 7)];
  __syncthreads();
  const float* yr = y + (size_t)row * DDIM;
  const float* p0 = P0 + (size_t)row * DDIM;
  const float* p1 = P1 + (size_t)row * DDIM;
  const float* xr = xd + (size_t)row * DDIM;
  float* o = out + (size_t)row * DDIM;
  for (int i = tid; i < DDIM; i += 256) {
    int m = i >> 7, dd = i & 127;
    float acc = yr[i] + p0[i] + p1[i] + bias[i];
#pragma unroll
    for (int n = 0; n < 8; n++) acc += cf[m][n] * xr[n * SDIMC + dd];
    o[i] = acc;
  }
}

extern "C" void kernel_launch(void* const* d_in, const int* in_sizes, int n_in,
                              void* d_out, int out_size, void* d_ws, size_t ws_size,
                              hipStream_t stream) {
  const float* x     = (const float*)d_in[0];
  const float* decay = (const float*)d_in[3];
  const float* gw    = (const float*)d_in[4];
  const float* gb    = (const float*)d_in[5];
  const float* phi   = (const float*)d_in[6];
  const float* ln1   = (const float*)d_in[7];
  const float* ln2   = (const float*)d_in[8];
  const float* w1    = (const float*)d_in[9];
  const float* b1    = (const float*)d_in[10];
  const float* w2    = (const float*)d_in[11];
  const float* b2    = (const float*)d_in[12];
  const float* ipw   = (const float*)d_in[13];
  const float* ipb   = (const float*)d_in[14];
  const float* ow    = (const float*)d_in[15];
  const float* obs   = (const float*)d_in[16];
  float* out = (float*)d_out;

  // ---- workspace layout (105 MB total) ----
  const size_t MB = 1048576ull;
  char* wsp = (char*)d_ws;
  float* SA   = (float*)(wsp);                 // 128 KB  chunk states / sums
  float* SIN  = (float*)(wsp + 131072ull);     // 128 KB  incoming states
  float* GRES = (float*)(wsp + 262144ull);     // 64 B
  float* HRES = (float*)(wsp + 262208ull);     // 256 B
  float* XD   = (float*)(wsp + 1 * MB);        // 16 MB   x_delta (f32), live to end
  float* AO   = (float*)(wsp + 17 * MB);       // 16 MB   y = x_delta + attn_out
  bf16*  NORM = (bf16*)(wsp + 33 * MB);        // 8 MB    normed/normed2 (dead after ffn1)
  bf16*  OB   = (bf16*)(wsp + 41 * MB);        // 8 MB    attn out (dead after outproj)
  bf16*  QKV  = (bf16*)(wsp + 49 * MB);        // 24 MB   (dead after flash)
  bf16*  VT   = (bf16*)(wsp + 73 * MB);        // 8 MB    (dead after flash)
  bf16*  HB   = (bf16*)(wsp + 49 * MB);        // 32 MB   gelu hidden, ALIASES QKV+VT
  bf16*  WIPW = (bf16*)(wsp + 81 * MB);        // 6 MB    in_proj_w bf16 (dead after qkv)
  bf16*  WOW  = (bf16*)(wsp + 87 * MB);        // 2 MB    out_w bf16 (dead after outproj)
  bf16*  W1B  = (bf16*)(wsp + 89 * MB);        // 8 MB    w1 bf16 (dead after ffn1)
  bf16*  W2B  = (bf16*)(wsp + 97 * MB);        // 8 MB    w2 bf16 (live thru ffn2)
  // ffn2 split-K partials (f32, 16 MB each), live from ffn2 thru final_k:
  // PK0 over NORM+OB (33-49 MB, dead), PK1 over WIPW/WOW/W1B (81-97 MB, dead)
  float* PK0  = (float*)(wsp + 33 * MB);
  float* PK1  = (float*)(wsp + 81 * MB);

  // 0: convert all GEMM weights f32 -> bf16 (single launch, float4 -> 8B pack)
  cvt_all<<<dim3(12 * DDIM * DDIM / 1024), dim3(256), 0, stream>>>(
      ipw, ow, w1, w2, WIPW, WOW, W1B, W2B);

  // 1-3: delta operator scan
  delta_passA<<<dim3(BB * NCH * DDIM / 256), dim3(256), 0, stream>>>(x, decay, SA);
  delta_passB<<<dim3(BB * DDIM / 256), dim3(256), 0, stream>>>(SA, decay, SIN);
  delta_passC<<<dim3(BB * NCH * DDIM / 256), dim3(256), 0, stream>>>(x, decay, SIN, XD, SA);
  // 4: gates + sinkhorn
  gates_sinkhorn<<<dim3(1), dim3(1024), 0, stream>>>(SA, gw, gb, phi, GRES, HRES);
  // 5: rmsnorm1 (XD -> NORM)
  rmsnorm_k<<<dim3(BB * SS), dim3(256), 0, stream>>>(XD, ln1, NORM);
  // 6: qkv = NORM @ in_proj_w.T + in_proj_b   [4096 x 3072]
  gemm_lds<1, 0><<<dim3(32, 24), dim3(256), 0, stream>>>(NORM, WIPW, ipb, nullptr,
                                                         QKV, BB * SS, 3 * DDIM, DDIM);
  // 7: V transpose
  vtrans<<<dim3(BB * NHEAD * (SS / 64)), dim3(256), 0, stream>>>(QKV, VT);
  // 8: flash attention -> OB (swapped QK^T, in-lane softmax, shared K/V frags)
  flash_attn<<<dim3(BB * NHEAD * 16), dim3(256), 0, stream>>>(QKV, VT, OB);
  // 9: out-proj + residual(XD) -> AO (= y)
  gemm_lds64<0, 2><<<dim3(64, 8), dim3(256), 0, stream>>>(OB, WOW, obs, XD,
                                                          AO, BB * SS, DDIM, DDIM);
  // 10: rmsnorm2 (AO -> NORM)
  rmsnorm_k<<<dim3(BB * SS), dim3(256), 0, stream>>>(AO, ln2, NORM);
  // 11: ffn1 + gelu -> HB   [4096 x 4096]  (HB aliases dead QKV/VT)
  gemm_lds<1, 1><<<dim3(32, 32), dim3(256), 0, stream>>>(NORM, W1B, b1, nullptr,
                                                         HB, BB * SS, 4 * DDIM, DDIM);
  // 12: ffn2 split-K=2, ONE launch (512 co-resident blocks) -> PK0/PK1
  gemm_part2<<<dim3(32, 8, 2), dim3(256), 0, stream>>>(HB, W2B, PK0, PK1,
                                                       BB * SS, DDIM, 2 * DDIM, 4 * DDIM);
  // 13: final out = y + PK0 + PK1 + b2 + mhc(XD)  (ffn2 epilogue fused here)
  final_k<<<dim3(BB * SS), dim3(256), 0, stream>>>(AO, PK0, PK1, b2, XD,
                                                   HRES, GRES, out);
}

// Round 5
// 417.376 us; speedup vs baseline: 1.0368x; 1.0368x over previous
//
#include <hip/hip_runtime.h>
#include <hip/hip_bf16.h>
#include <math.h>

// Problem constants
#define BB 2
#define SS 2048
#define DDIM 1024
#define NHEAD 16
#define NSTR 8
#define SDIMC 128
#define NCH 16      // chunks for delta scan
#define CLEN 128    // chunk length
#define EPSV 1e-6f

using bf16 = __hip_bfloat16;
typedef __attribute__((ext_vector_type(8))) __bf16 bf8;
typedef __attribute__((ext_vector_type(4))) __bf16 bf4v;
typedef __attribute__((ext_vector_type(4))) float f4;

__device__ __forceinline__ bf16 f2b(float v) { return __float2bfloat16(v); }
__device__ __forceinline__ bf8 ld8(const bf16* p) { return *(const bf8*)p; }
__device__ __forceinline__ f4 MFMA(bf8 a, bf8 b, f4 c) {
  return __builtin_amdgcn_mfma_f32_16x16x32_bf16(a, b, c, 0, 0, 0);
}
__device__ __forceinline__ float sigm(float x) { return 1.0f / (1.0f + expf(-x)); }
__device__ __forceinline__ float fexp2(float x) { return __builtin_amdgcn_exp2f(x); }

// fast gelu (exact-erf form) via Abramowitz-Stegun 7.1.26: |erf err| <= 1.5e-7,
// far below bf16 store rounding. hw rcp + hw exp2 instead of libm erff.
__device__ __forceinline__ float gelu_f(float v) {
  float x = v * 0.70710678118654752f;
  float ax = fabsf(x);
  float t = __builtin_amdgcn_rcpf(1.0f + 0.3275911f * ax);
  float p = ((((1.061405429f * t - 1.453152027f) * t + 1.421413741f) * t
              - 0.284496736f) * t + 0.254829592f) * t;
  float e = 1.0f - p * fexp2(-ax * ax * 1.4426950408889634f);
  e = copysignf(e, x);
  return 0.5f * v * (1.0f + e);
}

// async global->LDS 16B copy (m97 pattern; LDS dest must be uniform + lane*16)
__device__ __forceinline__ void glds16(bf16* l, const bf16* g) {
  __builtin_amdgcn_global_load_lds(
      (const __attribute__((address_space(1))) unsigned int*)g,
      (__attribute__((address_space(3))) unsigned int*)l, 16, 0, 0);
}

// ---------------- f32 -> bf16 weight conversion (all 4 weights, one launch) --
__global__ __launch_bounds__(256) void cvt_all(const float* __restrict__ ipw,
                                               const float* __restrict__ ow,
                                               const float* __restrict__ w1,
                                               const float* __restrict__ w2,
                                               bf16* __restrict__ WIPW,
                                               bf16* __restrict__ WOW,
                                               bf16* __restrict__ W1B,
                                               bf16* __restrict__ W2B) {
  const int S1 = 3 * DDIM * DDIM, S2 = S1 + DDIM * DDIM,
            S3 = S2 + 4 * DDIM * DDIM;
  int i4 = (blockIdx.x * 256 + threadIdx.x) * 4;   // grid covers 12.58M elems
  const float* src;
  bf16* dst;
  int off;
  if (i4 < S1)      { src = ipw; dst = WIPW; off = i4; }
  else if (i4 < S2) { src = ow;  dst = WOW;  off = i4 - S1; }
  else if (i4 < S3) { src = w1;  dst = W1B;  off = i4 - S2; }
  else              { src = w2;  dst = W2B;  off = i4 - S3; }
  float4 v = *(const float4*)(src + off);
  bf4v o;
  o[0] = (__bf16)v.x; o[1] = (__bf16)v.y; o[2] = (__bf16)v.z; o[3] = (__bf16)v.w;
  *(bf4v*)(dst + off) = o;                         // one 8B store, fully packed
}

// ---------------- Delta operator: 3-pass chunked affine scan ----------------
__global__ __launch_bounds__(256) void delta_passA(const float* __restrict__ x,
                                                   const float* __restrict__ decay,
                                                   float* __restrict__ SA) {
  int idx = blockIdx.x * 256 + threadIdx.x;      // [b][c][d]
  int d = idx % DDIM;
  int c = (idx / DDIM) % NCH;
  int b = idx / (DDIM * NCH);
  float beta = sigm(decay[d]);
  float omb = 1.0f - beta;
  const float* xp = x + ((size_t)(b * SS + c * CLEN)) * DDIM + d;
  float s = 0.0f;
  for (int j = 0; j < CLEN; j++) {
    float xv = xp[(size_t)j * DDIM];
    s = beta * s + omb * xv;
  }
  SA[idx] = s;
}

__global__ __launch_bounds__(256) void delta_passB(const float* __restrict__ SA,
                                                   const float* __restrict__ decay,
                                                   float* __restrict__ SIN) {
  int idx = blockIdx.x * 256 + threadIdx.x;      // [b][d]
  int d = idx % DDIM;
  int b = idx / DDIM;
  float beta = sigm(decay[d]);
  float p = beta;
  for (int i = 0; i < 7; i++) p *= p;            // beta^128
  float s = 0.0f;
  for (int c = 0; c < NCH; c++) {
    SIN[(b * NCH + c) * DDIM + d] = s;
    s = p * s + SA[(b * NCH + c) * DDIM + d];
  }
}

__global__ __launch_bounds__(256) void delta_passC(const float* __restrict__ x,
                                                   const float* __restrict__ decay,
                                                   const float* __restrict__ SIN,
                                                   float* __restrict__ XD,
                                                   float* __restrict__ SA) {
  int idx = blockIdx.x * 256 + threadIdx.x;      // [b][c][d]
  int d = idx % DDIM;
  int c = (idx / DDIM) % NCH;
  int b = idx / (DDIM * NCH);
  float beta = sigm(decay[d]);
  float omb = 1.0f - beta;
  const float* xp = x + ((size_t)(b * SS + c * CLEN)) * DDIM + d;
  float* xdp = XD + ((size_t)(b * SS + c * CLEN)) * DDIM + d;
  float s = SIN[idx];
  float sum = 0.0f;
  for (int j = 0; j < CLEN; j++) {
    float xv = xp[(size_t)j * DDIM];
    float o = xv - s;
    xdp[(size_t)j * DDIM] = o;
    sum += o;
    s = beta * s + omb * xv;
  }
  SA[idx] = sum;
}

// ---------------- gates (g_res) + sinkhorn ----------------
__global__ __launch_bounds__(1024) void gates_sinkhorn(const float* __restrict__ SA,
                                                       const float* __restrict__ gw,
                                                       const float* __restrict__ gb,
                                                       const float* __restrict__ phi,
                                                       float* __restrict__ gres,
                                                       float* __restrict__ hres) {
  int tid = threadIdx.x;
  int wave = tid >> 6, lane = tid & 63;
  int b = wave >> 3, j = wave & 7;               // 16 waves: (b, gate j)
  float acc = 0.0f;
  for (int d = lane; d < DDIM; d += 64) {
    float xs = 0.0f;
    for (int c = 0; c < NCH; c++) xs += SA[(b * NCH + c) * DDIM + d];
    xs *= (1.0f / (float)SS);
    acc += xs * gw[(2 * NSTR + j) * DDIM + d];
  }
  for (int off = 32; off > 0; off >>= 1) acc += __shfl_down(acc, off);
  if (lane == 0) gres[b * NSTR + j] = sigm(acc + gb[2 * NSTR + j]);
  __syncthreads();
  if (tid == 0) {
    float Km[8][8];
    for (int i = 0; i < 8; i++)
      for (int jj = 0; jj < 8; jj++) Km[i][jj] = expf(phi[i * 8 + jj]);
    for (int it = 0; it < 15; it++) {
      for (int i = 0; i < 8; i++) {
        float rs = 0.0f;
        for (int jj = 0; jj < 8; jj++) rs += Km[i][jj];
        float inv = 1.0f / rs;
        for (int jj = 0; jj < 8; jj++) Km[i][jj] *= inv;
      }
      for (int jj = 0; jj < 8; jj++) {
        float cs = 0.0f;
        for (int i = 0; i < 8; i++) cs += Km[i][jj];
        float inv = 1.0f / cs;
        for (int i = 0; i < 8; i++) Km[i][jj] *= inv;
      }
    }
    for (int i = 0; i < 8; i++)
      for (int jj = 0; jj < 8; jj++) hres[i * 8 + jj] = Km[i][jj];
  }
}

// ---------------- RMSNorm (f32 in -> bf16 out) ----------------
__global__ __launch_bounds__(256) void rmsnorm_k(const float* __restrict__ in,
                                                 const float* __restrict__ w,
                                                 bf16* __restrict__ out) {
  int row = blockIdx.x;
  const float* r = in + (size_t)row * DDIM;
  int tid = threadIdx.x;
  float ss = 0.0f;
  for (int i = tid; i < DDIM; i += 256) {
    float v = r[i];
    ss += v * v;
  }
  for (int off = 32; off > 0; off >>= 1) ss += __shfl_down(ss, off);
  __shared__ float red[4];
  if ((tid & 63) == 0) red[tid >> 6] = ss;
  __syncthreads();
  float tot = red[0] + red[1] + red[2] + red[3];
  float sc = rsqrtf(tot / (float)DDIM + EPSV);
  bf16* o = out + (size_t)row * DDIM;
  for (int i = tid; i < DDIM; i += 256) o[i] = f2b(r[i] * sc * w[i]);
}

// ======================= gemm256: 256x256 / BK=64 / 8-wave 8-phase ==========
// HK-style schedule (T2+T3+T4+T5) in plain HIP:
//  - LDS: A,B tiles stored as 16x32-elem SUBTILES (1024B contiguous each) with
//    st_16x32 swizzle (byte ^= ((byte>>9)&1)<<5 within subtile). glds16 writes
//    LINEAR dest; the SOURCE address is inverse-swizzled (involution) so the
//    swizzled READ round-trips (rule #21). Read conflict: 4-way (was 16-way).
//  - 4 phases per K-tile (C-quadrant each, 16 MFMA). B-frags read once per
//    tile (q=0, 12 ds_reads), A-frags per phase (4 ds_reads).
//  - Stage schedule per tile t (buf c=t&1): q0:A(t+1)h0, q1:A(t+1)h1 -> buf
//    c^1 (A region dead since t-1:q3); q2:B(t+2)h0, q3:B(t+2)h1 -> buf c
//    (B region dead since t:q0). Wait vmcnt(4) at q3 only: leaves B(t+2)
//    (4 loads) in flight, guarantees A(t+1)+B(t+1) landed (FIFO).
//  - raw s_barrier + "" memory clobbers pin LDS ops to their phase;
//    setprio(1) around the MFMA cluster (T5, pays under phase role-split).
// EPI: 0 = bf16 out (+bias), 1 = bf16 out gelu(x+bias)
template <int EPI>
__global__ __launch_bounds__(512, 2) void gemm256(const bf16* __restrict__ Ag,
                                                  const bf16* __restrict__ Wg,
                                                  const float* __restrict__ bias,
                                                  bf16* __restrict__ outp,
                                                  int M, int N, int K, int nby) {
  __shared__ __align__(16) bf16 As[2][16384];   // 2 x 32KB
  __shared__ __align__(16) bf16 Bs[2][16384];   // 2 x 32KB  (total 128KB)
  int nwg = gridDim.x;
  int cpx = nwg >> 3;                            // nwg % 8 == 0 (bijective T1)
  int l = (blockIdx.x & 7) * cpx + (blockIdx.x >> 3);
  int bm = l / nby, bn = l % nby;                // row-major: XCD keeps A-panel
  int m0 = bm * 256, n0 = bn * 256;
  int tid = threadIdx.x;
  int lane = tid & 63, wv = tid >> 6;
  int ml = lane & 15, quad = lane >> 4;
  int wrow = wv >> 2, wcol = wv & 3;             // 2x4 wave grid, 128x64 /wave

  // staging: per-thread (h=half, j=load) -> global element offset + LDS slot.
  // dest byte b = h*16384 + tid*16 + j*8192 (linear, wave-uniform + lane*16);
  // decode subtile s=b>>10 (srow=s>>1, scol=s&1), within w=b&1023,
  // logical wl = w ^ ((w>>9&1)<<5)  (involution) -> (r16, c32).
  size_t aoff[2][2], boff[2][2];
  int lof[2][2];
#pragma unroll
  for (int h = 0; h < 2; h++)
#pragma unroll
    for (int j = 0; j < 2; j++) {
      int b = tid * 16 + j * 8192;
      int s = b >> 10, w = b & 1023;
      int wl = w ^ (((w >> 9) & 1) << 5);
      int row = h * 128 + (s >> 1) * 16 + (wl >> 6);
      int col = (s & 1) * 32 + ((wl & 63) >> 1);
      aoff[h][j] = (size_t)(m0 + row) * K + col;
      boff[h][j] = (size_t)(n0 + row) * K + col;
      lof[h][j] = (h * 16384 + b) >> 1;
    }
  // read-side per-thread swizzled within-subtile offset (bf16 units):
  // w = ml*64 + quad*16, ^32 iff ml>=8 (bit9 of w)
  int wq2 = ((((ml << 6) + (quad << 4)) ^ (((int)(ml >= 8)) << 5))) >> 1;

#define SA_(c, kt, h) { glds16(&As[c][lof[h][0]], Ag + aoff[h][0] + (size_t)(kt) * 64); \
                        glds16(&As[c][lof[h][1]], Ag + aoff[h][1] + (size_t)(kt) * 64); }
#define SB_(c, kt, h) { glds16(&Bs[c][lof[h][0]], Wg + boff[h][0] + (size_t)(kt) * 64); \
                        glds16(&Bs[c][lof[h][1]], Wg + boff[h][1] + (size_t)(kt) * 64); }

  // prologue: A(0)+B(0) -> buf0, B(1) -> buf1; vmcnt(4) leaves B(1) in flight
  SA_(0, 0, 0); SA_(0, 0, 1);
  SB_(0, 0, 0); SB_(0, 0, 1);
  SB_(1, 1, 0); SB_(1, 1, 1);
  f4 acc[8][4] = {};
  asm volatile("s_waitcnt vmcnt(4)" ::: "memory");
  __builtin_amdgcn_s_barrier();
  asm volatile("" ::: "memory");

  int T = K >> 6;                                // K-tiles (K=1024 -> 16)
  for (int t = 0; t < T; t++) {
    int c = t & 1;
    bf8 bfrag[4][2];                             // held across the 4 phases
#pragma unroll
    for (int q = 0; q < 4; q++) {
      // ds-loads for this phase (compiler ds_read_b128, 4-way conflict max)
      bf8 af[2][2];
#pragma unroll
      for (int mi2 = 0; mi2 < 2; mi2++)
#pragma unroll
        for (int kk = 0; kk < 2; kk++)
          af[mi2][kk] =
              ld8(&As[c][(((wrow * 8 + q * 2 + mi2) * 2 + kk) << 9) + wq2]);
      if (q == 0) {
#pragma unroll
        for (int ni = 0; ni < 4; ni++)
#pragma unroll
          for (int kk = 0; kk < 2; kk++)
            bfrag[ni][kk] =
                ld8(&Bs[c][(((wcol * 4 + ni) * 2 + kk) << 9) + wq2]);
      }
      // stage one half-tile (schedule in header comment)
      if (q == 0 && t + 1 < T) SA_(c ^ 1, t + 1, 0);
      if (q == 1 && t + 1 < T) SA_(c ^ 1, t + 1, 1);
      if (q == 2 && t + 2 < T) SB_(c, t + 2, 0);
      if (q == 3 && t + 2 < T) SB_(c, t + 2, 1);
      __builtin_amdgcn_s_barrier();
      asm volatile("s_waitcnt lgkmcnt(0)" ::: "memory");
      __builtin_amdgcn_s_setprio(1);
#pragma unroll
      for (int mi2 = 0; mi2 < 2; mi2++)
#pragma unroll
        for (int ni = 0; ni < 4; ni++)
#pragma unroll
          for (int kk = 0; kk < 2; kk++)
            acc[q * 2 + mi2][ni] =
                MFMA(af[mi2][kk], bfrag[ni][kk], acc[q * 2 + mi2][ni]);
      __builtin_amdgcn_s_setprio(0);
      if (q == 3) {                              // once per K-tile (T4)
        if (t + 2 < T) {
          asm volatile("s_waitcnt vmcnt(4)" ::: "memory");
        } else if (t + 1 < T) {
          asm volatile("s_waitcnt vmcnt(0)" ::: "memory");
        }
      }
      __builtin_amdgcn_s_barrier();
      asm volatile("" ::: "memory");
    }
  }
  // epilogue: C[row][col], row = m-frag, col = n-frag (verified layout)
#pragma unroll
  for (int mi = 0; mi < 8; mi++)
#pragma unroll
    for (int ni = 0; ni < 4; ni++)
#pragma unroll
      for (int r = 0; r < 4; r++) {
        int row = m0 + wrow * 128 + mi * 16 + quad * 4 + r;
        int col = n0 + wcol * 64 + ni * 16 + ml;
        float v = acc[mi][ni][r] + bias[col];
        if (EPI == 1) v = gelu_f(v);
        outp[(size_t)row * N + col] = f2b(v);
      }
#undef SA_
#undef SB_
}

// ------- ffn2 split-K=2, ONE launch, grid (32,8,2): z picks K-slice+buffer ---
// double-buffered single-barrier structure (round-3 form; counted-vmcnt at
// 128^2/2-barrier measured REGRESSIVE -> reverted)
__global__ __launch_bounds__(256) void gemm_part2(const bf16* __restrict__ A,
                                                  const bf16* __restrict__ W,
                                                  float* __restrict__ P0,
                                                  float* __restrict__ P1,
                                                  int M, int N, int KS, int LDK) {
  __shared__ bf16 As[2][128 * 32];
  __shared__ bf16 Bs[2][128 * 32];
  int tid = threadIdx.x;
  int lane = tid & 63, wv = tid >> 6;
  int ml = lane & 15, quad = lane >> 4;
  int wr = wv >> 1, wc = wv & 1;
  int m0 = blockIdx.x * 128, n0 = blockIdx.y * 128;
  const bf16* Ab = A + blockIdx.z * KS;
  const bf16* Wb = W + blockIdx.z * KS;
  float* P = blockIdx.z ? P1 : P0;
  const bf16* ga[2];
  const bf16* gb[2];
  int lofs[2];
#pragma unroll
  for (int it = 0; it < 2; it++) {
    int c = it * 256 + tid;
    int row = c >> 2, kc = (c & 3) * 8;
    ga[it] = Ab + (size_t)(m0 + row) * LDK + kc;
    gb[it] = Wb + (size_t)(n0 + row) * LDK + kc;
    lofs[it] = c * 8;
  }
#pragma unroll
  for (int it = 0; it < 2; it++) {
    glds16(&As[0][lofs[it]], ga[it]);
    glds16(&Bs[0][lofs[it]], gb[it]);
  }
  f4 acc[4][4] = {};
  int nk = KS >> 5;
  int cur = 0;
  __syncthreads();
  for (int t = 0; t < nk; t++) {
    if (t + 1 < nk) {
      int ko = (t + 1) * 32;
#pragma unroll
      for (int it = 0; it < 2; it++) {
        glds16(&As[cur ^ 1][lofs[it]], ga[it] + ko);
        glds16(&Bs[cur ^ 1][lofs[it]], gb[it] + ko);
      }
    }
    bf8 af[4], bfr[4];
#pragma unroll
    for (int mi = 0; mi < 4; mi++)
      af[mi] = ld8(&As[cur][(wr * 64 + mi * 16 + ml) * 32 + quad * 8]);
#pragma unroll
    for (int ni = 0; ni < 4; ni++)
      bfr[ni] = ld8(&Bs[cur][(wc * 64 + ni * 16 + ml) * 32 + quad * 8]);
#pragma unroll
    for (int mi = 0; mi < 4; mi++)
#pragma unroll
      for (int ni = 0; ni < 4; ni++)
        acc[mi][ni] = MFMA(af[mi], bfr[ni], acc[mi][ni]);
    __syncthreads();
    cur ^= 1;
  }
#pragma unroll
  for (int mi = 0; mi < 4; mi++)
#pragma unroll
    for (int ni = 0; ni < 4; ni++)
#pragma unroll
      for (int r = 0; r < 4; r++) {
        int row = m0 + wr * 64 + mi * 16 + quad * 4 + r;
        int col = n0 + wc * 64 + ni * 16 + ml;
        P[(size_t)row * N + col] = acc[mi][ni][r];
      }
}

// ------- MFMA GEMM, BM=64 x BN=128 variant, double-buffered (round-3 form) --
template <int ODT, int EPI>
__global__ __launch_bounds__(256) void gemm_lds64(const bf16* __restrict__ A,
                                                  const bf16* __restrict__ W,
                                                  const float* __restrict__ bias,
                                                  const float* __restrict__ res,
                                                  void* __restrict__ outp,
                                                  int M, int N, int K) {
  __shared__ bf16 As[2][64 * 32];
  __shared__ bf16 Bs[2][128 * 32];
  int tid = threadIdx.x;
  int lane = tid & 63, wv = tid >> 6;
  int ml = lane & 15, quad = lane >> 4;
  int wr = wv & 1, wc = wv >> 1;        // wave tile: 32 rows x 64 cols
  int m0 = blockIdx.x * 64, n0 = blockIdx.y * 128;
  const bf16* gaA;
  const bf16* gb[2];
  int lofA, lofs[2];
  {
    int c = tid;                        // A: 256 chunks
    int row = c >> 2, kc = (c & 3) * 8;
    gaA = A + (size_t)(m0 + row) * K + kc;
    lofA = c * 8;
  }
#pragma unroll
  for (int it = 0; it < 2; it++) {      // B: 512 chunks
    int c = it * 256 + tid;
    int row = c >> 2, kc = (c & 3) * 8;
    gb[it] = W + (size_t)(n0 + row) * K + kc;
    lofs[it] = c * 8;
  }
  glds16(&As[0][lofA], gaA);
#pragma unroll
  for (int it = 0; it < 2; it++) glds16(&Bs[0][lofs[it]], gb[it]);
  f4 acc[2][4] = {};
  int nk = K >> 5;
  int cur = 0;
  __syncthreads();
  for (int t = 0; t < nk; t++) {
    if (t + 1 < nk) {
      int ko = (t + 1) * 32;
      glds16(&As[cur ^ 1][lofA], gaA + ko);
#pragma unroll
      for (int it = 0; it < 2; it++) glds16(&Bs[cur ^ 1][lofs[it]], gb[it] + ko);
    }
    bf8 af[2], bfr[4];
#pragma unroll
    for (int mi = 0; mi < 2; mi++)
      af[mi] = ld8(&As[cur][(wr * 32 + mi * 16 + ml) * 32 + quad * 8]);
#pragma unroll
    for (int ni = 0; ni < 4; ni++)
      bfr[ni] = ld8(&Bs[cur][(wc * 64 + ni * 16 + ml) * 32 + quad * 8]);
#pragma unroll
    for (int mi = 0; mi < 2; mi++)
#pragma unroll
      for (int ni = 0; ni < 4; ni++)
        acc[mi][ni] = MFMA(af[mi], bfr[ni], acc[mi][ni]);
    __syncthreads();
    cur ^= 1;
  }
#pragma unroll
  for (int mi = 0; mi < 2; mi++)
#pragma unroll
    for (int ni = 0; ni < 4; ni++)
#pragma unroll
      for (int r = 0; r < 4; r++) {
        int row = m0 + wr * 32 + mi * 16 + quad * 4 + r;
        int col = n0 + wc * 64 + ni * 16 + ml;
        size_t idx = (size_t)row * N + col;
        float v = acc[mi][ni][r] + bias[col];
        if (EPI == 1) v = gelu_f(v);
        if (EPI == 2) v += res[idx];
        if (ODT == 1) ((bf16*)outp)[idx] = f2b(v);
        else ((float*)outp)[idx] = v;
      }
}

// ---------------- V transpose: VT[b,h,d,s] = qkv[b,s,2D + h*64 + d] --------
__global__ __launch_bounds__(256) void vtrans(const bf16* __restrict__ qkv,
                                              bf16* __restrict__ VT) {
  int bid = blockIdx.x;
  int st = bid % (SS / 64);
  int h = (bid / (SS / 64)) % NHEAD;
  int b = bid / ((SS / 64) * NHEAD);
  __shared__ bf16 tile[64][65];
  int s0 = st * 64;
  int tid = threadIdx.x;
  for (int it = 0; it < 16; it++) {
    int sl = it * 4 + (tid >> 6), dl = tid & 63;
    tile[sl][dl] = qkv[(size_t)(b * SS + s0 + sl) * (3 * DDIM) + 2 * DDIM + h * 64 + dl];
  }
  __syncthreads();
  for (int it = 0; it < 16; it++) {
    int dl = it * 4 + (tid >> 6), sl = tid & 63;
    VT[((size_t)(b * NHEAD + h) * 64 + dl) * SS + s0 + sl] = tile[sl][dl];
  }
}

// ---- Flash attention v10: SWAPPED QK^T (mfma(K,Q) -> S^T, lane owns one
// q-row) -> in-lane softmax: 8 shuffles/phase, packed b64 P-writes, K/V
// fragments loaded ONCE per tile shared by both antithetic phases.
__device__ __forceinline__ void qk_softmax(bool active, int kt, int q0, int nkt,
                                           const bf8 kf[4][2], const bf8* qf,
                                           f4* oacc, float& m, float& l,
                                           bf8* pf, bf16 (*pl)[72],
                                           int ml, int quad, int k0) {
  if (!active) return;                   // block-uniform condition
  const float SC = 0.125f * 1.44269504089f;  // 1/sqrt(64) * log2(e)
  f4 s[4] = {{0,0,0,0},{0,0,0,0},{0,0,0,0},{0,0,0,0}};
  __builtin_amdgcn_s_setprio(1);
#pragma unroll
  for (int kk = 0; kk < 2; kk++)
#pragma unroll
    for (int c = 0; c < 4; c++)
      s[c] = MFMA(kf[c][kk], qf[kk], s[c]);   // S^T = K . Q^T
  __builtin_amdgcn_s_setprio(0);
  if (kt == nkt - 1) {                   // diagonal tile: causal mask
    int qi = q0 + ml;
#pragma unroll
    for (int c = 0; c < 4; c++)
#pragma unroll
      for (int r = 0; r < 4; r++)
        if (k0 + c * 16 + quad * 4 + r > qi) s[c][r] = -1e30f;
  }
  // in-lane max over 16 k-values, then 2-step quad reduce
  float mx = s[0][0];
#pragma unroll
  for (int c = 0; c < 4; c++)
#pragma unroll
    for (int r = 0; r < 4; r++) mx = fmaxf(mx, s[c][r]);
  mx = fmaxf(mx, __shfl_xor(mx, 16));
  mx = fmaxf(mx, __shfl_xor(mx, 32));
  float mn = fmaxf(m, mx * SC);
  float alpha = fexp2(m - mn);
  float rs = 0.0f;
  float p[4][4];
#pragma unroll
  for (int c = 0; c < 4; c++)
#pragma unroll
    for (int r = 0; r < 4; r++) {
      p[c][r] = fexp2(__builtin_fmaf(s[c][r], SC, -mn));
      rs += p[c][r];
    }
  rs += __shfl_xor(rs, 16);
  rs += __shfl_xor(rs, 32);
  l = l * alpha + rs;
  m = mn;
  // redistribute alpha (state row q=ml) to O-layout rows (q=quad*4+r)
  float alr[4];
#pragma unroll
  for (int r = 0; r < 4; r++) alr[r] = __shfl(alpha, quad * 4 + r);
#pragma unroll
  for (int c = 0; c < 4; c++)
#pragma unroll
    for (int r = 0; r < 4; r++) oacc[c][r] *= alr[r];
  // P is lane-local: pack 4 bf16 per chunk, one b64 write each
#pragma unroll
  for (int c = 0; c < 4; c++) {
    bf4v w;
#pragma unroll
    for (int r = 0; r < 4; r++) w[r] = (__bf16)p[c][r];
    *(bf4v*)&pl[ml][c * 16 + quad * 4] = w;
  }
#pragma unroll
  for (int kk = 0; kk < 2; kk++) pf[kk] = ld8(&pl[ml][kk * 32 + quad * 8]);
}

__device__ __forceinline__ void pv_acc(bool active, const bf8* pf,
                                       const bf8 vf[4][2], f4* oacc) {
  if (!active) return;
  __builtin_amdgcn_s_setprio(1);
#pragma unroll
  for (int c = 0; c < 4; c++)
#pragma unroll
    for (int kk = 0; kk < 2; kk++)
      oacc[c] = MFMA(pf[kk], vf[c][kk], oacc[c]);
  __builtin_amdgcn_s_setprio(0);
}

__global__ __launch_bounds__(256) void flash_attn(const bf16* __restrict__ qkv,
                                                  const bf16* __restrict__ VT,
                                                  bf16* __restrict__ obuf) {
  // T1 XCD swizzle: each XCD owns 4 complete (b,h) groups -> K/V L2-resident
  int rb = blockIdx.x;
  int bid = (rb & 7) * 64 + (rb >> 3);
  // complementary blk pairing (pair sums to 49 tiles)
  int j = bid & 15;
  int blk = (j & 1) ? (15 - (j >> 1)) : (j >> 1);
  int h = (bid >> 4) & 15;
  int b = bid >> 8;
  int tid = threadIdx.x;
  int wv = tid >> 6, lane = tid & 63;
  int ml = lane & 15, quad = lane >> 4;
  int idx0 = blk * 4 + wv;              // phase-0 subtile (16 Q rows)
  int idx1 = 127 - idx0;                // phase-1 (antithetic)
  int q0a = idx0 * 16, q0b = idx1 * 16;
  int nkt0 = blk + 1;                   // block-uniform
  int nkt1 = 32 - blk;                  // block-uniform; nkt1 >= nkt0
  int maxn = nkt1;

  __shared__ __align__(16) bf16 Ks[2][64 * 64];
  __shared__ __align__(16) bf16 Vs[2][64 * 64];
  __shared__ __align__(16) bf16 plds[4][2][16][72];  // per-wave, per-phase
  bf16 (*plA)[72] = plds[wv][0];
  bf16 (*plB)[72] = plds[wv][1];

  bf8 qfa[2], qfb[2];
#pragma unroll
  for (int kk = 0; kk < 2; kk++) {
    qfa[kk] = ld8(qkv + (size_t)(b * SS + q0a + ml) * (3 * DDIM) + h * 64 + kk * 32 + quad * 8);
    qfb[kk] = ld8(qkv + (size_t)(b * SS + q0b + ml) * (3 * DDIM) + h * 64 + kk * 32 + quad * 8);
  }
  f4 oacca[4] = {{0,0,0,0},{0,0,0,0},{0,0,0,0},{0,0,0,0}};
  f4 oaccb[4] = {{0,0,0,0},{0,0,0,0},{0,0,0,0},{0,0,0,0}};
  float ma = -1e30f, la = 0.0f, mb = -1e30f, lb = 0.0f;

  const bf16* kglob = qkv + (size_t)b * SS * (3 * DDIM) + DDIM + h * 64;
  const bf16* vglob = VT + (size_t)(b * NHEAD + h) * 64 * SS;

  // prologue: stage tile 0 into buffer 0 (swizzled SOURCE, lane-linear dest)
#pragma unroll
  for (int it = 0; it < 2; it++) {
    int lam = it * 256 + tid;
    int row = lam >> 3;
    int ch = (lam & 7) ^ (row & 7);
    glds16(&Ks[0][lam * 8], kglob + (size_t)row * (3 * DDIM) + ch * 8);
    glds16(&Vs[0][lam * 8], vglob + (size_t)row * SS + ch * 8);
  }
  __syncthreads();
  int cur = 0;
  for (int kt = 0; kt < maxn; kt++) {
    int k0 = kt * 64;
    if (kt + 1 < maxn) {                // prefetch next K/V tile
      int k0n = (kt + 1) * 64;
#pragma unroll
      for (int it = 0; it < 2; it++) {
        int lam = it * 256 + tid;
        int row = lam >> 3;
        int ch = (lam & 7) ^ (row & 7);
        glds16(&Ks[cur ^ 1][lam * 8], kglob + (size_t)(k0n + row) * (3 * DDIM) + ch * 8);
        glds16(&Vs[cur ^ 1][lam * 8], vglob + (size_t)row * SS + k0n + ch * 8);
      }
    }
    bool act0 = kt < nkt0;              // block-uniform
    bf8 kf[4][2];
#pragma unroll
    for (int kk = 0; kk < 2; kk++)
#pragma unroll
      for (int c = 0; c < 4; c++) {
        int chunk = ((c * 16 + ml) << 3) + ((kk * 4 + quad) ^ (ml & 7));
        kf[c][kk] = ld8(&Ks[cur][chunk * 8]);
      }
    bf8 pfa[2], pfb[2];
    qk_softmax(act0, kt, q0a, nkt0, kf, qfa, oacca, ma, la, pfa, plA, ml, quad, k0);
    qk_softmax(true, kt, q0b, nkt1, kf, qfb, oaccb, mb, lb, pfb, plB, ml, quad, k0);
    bf8 vf[4][2];
#pragma unroll
    for (int kk = 0; kk < 2; kk++)
#pragma unroll
      for (int c = 0; c < 4; c++) {
        int chunk = ((c * 16 + ml) << 3) + ((kk * 4 + quad) ^ (ml & 7));
        vf[c][kk] = ld8(&Vs[cur][chunk * 8]);
      }
    pv_acc(act0, pfa, vf, oacca);
    pv_acc(true, pfb, vf, oaccb);
    __syncthreads();                    // vmcnt(0)+lgkmcnt(0)+barrier
    cur ^= 1;
  }
  // redistribute l (state row q=ml) to O-layout rows, then store
  float lna[4], lnb[4];
#pragma unroll
  for (int r = 0; r < 4; r++) {
    lna[r] = __shfl(la, quad * 4 + r);
    lnb[r] = __shfl(lb, quad * 4 + r);
  }
#pragma unroll
  for (int c = 0; c < 4; c++)
#pragma unroll
    for (int r = 0; r < 4; r++) {
      int rowa = q0a + quad * 4 + r;
      int rowb = q0b + quad * 4 + r;
      obuf[(size_t)(b * SS + rowa) * DDIM + h * 64 + c * 16 + ml] =
          f2b(oacca[c][r] / lna[r]);
      obuf[(size_t)(b * SS + rowb) * DDIM + h * 64 + c * 16 + ml] =
          f2b(oaccb[c][r] / lnb[r]);
    }
}

// ---------------- final: out = y + P0 + P1 + b2 + mhc(XD) ----------------
__global__ __launch_bounds__(256) void final_k(const float* __restrict__ y,
                                               const float* __restrict__ P0,
                                               const float* __restrict__ P1,
                                               const float* __restrict__ bias,
                                               const float* __restrict__ xd,
                                               const float* __restrict__ hres,
                                               const float* __restrict__ gres,
                                               float* __restrict__ out) {
  int row = blockIdx.x;  // [B*S]
  int b = row / SS;
  int tid = threadIdx.x;
  __shared__ float cf[8][8];
  if (tid < 64) cf[tid >> 3][tid & 7] = hres[tid] * gres[b * NSTR + (tid & 7)];
  __syncthreads();
  const float* yr = y + (size_t)row * DDIM;
  const float* p0 = P0 + (size_t)row * DDIM;
  const float* p1 = P1 + (size_t)row * DDIM;
  const float* xr = xd + (size_t)row * DDIM;
  float* o = out + (size_t)row * DDIM;
  for (int i = tid; i < DDIM; i += 256) {
    int m = i >> 7, dd = i & 127;
    float acc = yr[i] + p0[i] + p1[i] + bias[i];
#pragma unroll
    for (int n = 0; n < 8; n++) acc += cf[m][n] * xr[n * SDIMC + dd];
    o[i] = acc;
  }
}

extern "C" void kernel_launch(void* const* d_in, const int* in_sizes, int n_in,
                              void* d_out, int out_size, void* d_ws, size_t ws_size,
                              hipStream_t stream) {
  const float* x     = (const float*)d_in[0];
  const float* decay = (const float*)d_in[3];
  const float* gw    = (const float*)d_in[4];
  const float* gb    = (const float*)d_in[5];
  const float* phi   = (const float*)d_in[6];
  const float* ln1   = (const float*)d_in[7];
  const float* ln2   = (const float*)d_in[8];
  const float* w1    = (const float*)d_in[9];
  const float* b1    = (const float*)d_in[10];
  const float* w2    = (const float*)d_in[11];
  const float* b2    = (const float*)d_in[12];
  const float* ipw   = (const float*)d_in[13];
  const float* ipb   = (const float*)d_in[14];
  const float* ow    = (const float*)d_in[15];
  const float* obs   = (const float*)d_in[16];
  float* out = (float*)d_out;

  // ---- workspace layout (105 MB total) ----
  const size_t MB = 1048576ull;
  char* wsp = (char*)d_ws;
  float* SA   = (float*)(wsp);                 // 128 KB  chunk states / sums
  float* SIN  = (float*)(wsp + 131072ull);     // 128 KB  incoming states
  float* GRES = (float*)(wsp + 262144ull);     // 64 B
  float* HRES = (float*)(wsp + 262208ull);     // 256 B
  float* XD   = (float*)(wsp + 1 * MB);        // 16 MB   x_delta (f32), live to end
  float* AO   = (float*)(wsp + 17 * MB);       // 16 MB   y = x_delta + attn_out
  bf16*  NORM = (bf16*)(wsp + 33 * MB);        // 8 MB    normed/normed2 (dead after ffn1)
  bf16*  OB   = (bf16*)(wsp + 41 * MB);        // 8 MB    attn out (dead after outproj)
  bf16*  QKV  = (bf16*)(wsp + 49 * MB);        // 24 MB   (dead after flash)
  bf16*  VT   = (bf16*)(wsp + 73 * MB);        // 8 MB    (dead after flash)
  bf16*  HB   = (bf16*)(wsp + 49 * MB);        // 32 MB   gelu hidden, ALIASES QKV+VT
  bf16*  WIPW = (bf16*)(wsp + 81 * MB);        // 6 MB    in_proj_w bf16 (dead after qkv)
  bf16*  WOW  = (bf16*)(wsp + 87 * MB);        // 2 MB    out_w bf16 (dead after outproj)
  bf16*  W1B  = (bf16*)(wsp + 89 * MB);        // 8 MB    w1 bf16 (dead after ffn1)
  bf16*  W2B  = (bf16*)(wsp + 97 * MB);        // 8 MB    w2 bf16 (live thru ffn2)
  // ffn2 split-K partials (f32, 16 MB each), live from ffn2 thru final_k
  float* PK0  = (float*)(wsp + 33 * MB);
  float* PK1  = (float*)(wsp + 81 * MB);

  // 0: convert all GEMM weights f32 -> bf16
  cvt_all<<<dim3(12 * DDIM * DDIM / 1024), dim3(256), 0, stream>>>(
      ipw, ow, w1, w2, WIPW, WOW, W1B, W2B);

  // 1-3: delta operator scan
  delta_passA<<<dim3(BB * NCH * DDIM / 256), dim3(256), 0, stream>>>(x, decay, SA);
  delta_passB<<<dim3(BB * DDIM / 256), dim3(256), 0, stream>>>(SA, decay, SIN);
  delta_passC<<<dim3(BB * NCH * DDIM / 256), dim3(256), 0, stream>>>(x, decay, SIN, XD, SA);
  // 4: gates + sinkhorn
  gates_sinkhorn<<<dim3(1), dim3(1024), 0, stream>>>(SA, gw, gb, phi, GRES, HRES);
  // 5: rmsnorm1 (XD -> NORM)
  rmsnorm_k<<<dim3(BB * SS), dim3(256), 0, stream>>>(XD, ln1, NORM);
  // 6: qkv = NORM @ in_proj_w.T + in_proj_b   [4096 x 3072] -- 8-phase 256^2
  gemm256<0><<<dim3(192), dim3(512), 0, stream>>>(NORM, WIPW, ipb, QKV,
                                                  BB * SS, 3 * DDIM, DDIM, 12);
  // 7: V transpose
  vtrans<<<dim3(BB * NHEAD * (SS / 64)), dim3(256), 0, stream>>>(QKV, VT);
  // 8: flash attention -> OB (swapped QK^T, in-lane softmax, shared K/V frags)
  flash_attn<<<dim3(BB * NHEAD * 16), dim3(256), 0, stream>>>(QKV, VT, OB);
  // 9: out-proj + residual(XD) -> AO (= y)
  gemm_lds64<0, 2><<<dim3(64, 8), dim3(256), 0, stream>>>(OB, WOW, obs, XD,
                                                          AO, BB * SS, DDIM, DDIM);
  // 10: rmsnorm2 (AO -> NORM)
  rmsnorm_k<<<dim3(BB * SS), dim3(256), 0, stream>>>(AO, ln2, NORM);
  // 11: ffn1 + gelu -> HB   [4096 x 4096] -- 8-phase 256^2
  gemm256<1><<<dim3(256), dim3(512), 0, stream>>>(NORM, W1B, b1, HB,
                                                  BB * SS, 4 * DDIM, DDIM, 16);
  // 12: ffn2 split-K=2, ONE launch (512 co-resident blocks) -> PK0/PK1
  gemm_part2<<<dim3(32, 8, 2), dim3(256), 0, stream>>>(HB, W2B, PK0, PK1,
                                                       BB * SS, DDIM, 2 * DDIM, 4 * DDIM);
  // 13: final out = y + PK0 + PK1 + b2 + mhc(XD)
  final_k<<<dim3(BB * SS), dim3(256), 0, stream>>>(AO, PK0, PK1, b2, XD,
                                                   HRES, GRES, out);
}

// Round 6
// 395.758 us; speedup vs baseline: 1.0935x; 1.0546x over previous
//
#include <hip/hip_runtime.h>
#include <hip/hip_bf16.h>
#include <math.h>

// Problem constants
#define BB 2
#define SS 2048
#define DDIM 1024
#define NHEAD 16
#define NSTR 8
#define SDIMC 128
#define NCH 16      // chunks for delta scan
#define CLEN 128    // chunk length
#define EPSV 1e-6f

using bf16 = __hip_bfloat16;
typedef __attribute__((ext_vector_type(8))) __bf16 bf8;
typedef __attribute__((ext_vector_type(4))) __bf16 bf4v;
typedef __attribute__((ext_vector_type(4))) float f4;

__device__ __forceinline__ bf16 f2b(float v) { return __float2bfloat16(v); }
__device__ __forceinline__ bf8 ld8(const bf16* p) { return *(const bf8*)p; }
__device__ __forceinline__ f4 MFMA(bf8 a, bf8 b, f4 c) {
  return __builtin_amdgcn_mfma_f32_16x16x32_bf16(a, b, c, 0, 0, 0);
}
__device__ __forceinline__ float sigm(float x) { return 1.0f / (1.0f + expf(-x)); }
__device__ __forceinline__ float fexp2(float x) { return __builtin_amdgcn_exp2f(x); }
__device__ __forceinline__ float max3f(float a, float b, float c) {
  return fmaxf(fmaxf(a, b), c);   // clang fuses to v_max3_f32
}

// fast gelu (exact-erf form) via Abramowitz-Stegun 7.1.26: |erf err| <= 1.5e-7
__device__ __forceinline__ float gelu_f(float v) {
  float x = v * 0.70710678118654752f;
  float ax = fabsf(x);
  float t = __builtin_amdgcn_rcpf(1.0f + 0.3275911f * ax);
  float p = ((((1.061405429f * t - 1.453152027f) * t + 1.421413741f) * t
              - 0.284496736f) * t + 0.254829592f) * t;
  float e = 1.0f - p * fexp2(-ax * ax * 1.4426950408889634f);
  e = copysignf(e, x);
  return 0.5f * v * (1.0f + e);
}

// async global->LDS 16B copy (m97 pattern; LDS dest must be uniform + lane*16)
__device__ __forceinline__ void glds16(bf16* l, const bf16* g) {
  __builtin_amdgcn_global_load_lds(
      (const __attribute__((address_space(1))) unsigned int*)g,
      (__attribute__((address_space(3))) unsigned int*)l, 16, 0, 0);
}

// ---------------- f32 -> bf16 weight conversion (all 4 weights, one launch) --
__global__ __launch_bounds__(256) void cvt_all(const float* __restrict__ ipw,
                                               const float* __restrict__ ow,
                                               const float* __restrict__ w1,
                                               const float* __restrict__ w2,
                                               bf16* __restrict__ WIPW,
                                               bf16* __restrict__ WOW,
                                               bf16* __restrict__ W1B,
                                               bf16* __restrict__ W2B) {
  const int S1 = 3 * DDIM * DDIM, S2 = S1 + DDIM * DDIM,
            S3 = S2 + 4 * DDIM * DDIM;
  int i4 = (blockIdx.x * 256 + threadIdx.x) * 4;   // grid covers 12.58M elems
  const float* src;
  bf16* dst;
  int off;
  if (i4 < S1)      { src = ipw; dst = WIPW; off = i4; }
  else if (i4 < S2) { src = ow;  dst = WOW;  off = i4 - S1; }
  else if (i4 < S3) { src = w1;  dst = W1B;  off = i4 - S2; }
  else              { src = w2;  dst = W2B;  off = i4 - S3; }
  float4 v = *(const float4*)(src + off);
  bf4v o;
  o[0] = (__bf16)v.x; o[1] = (__bf16)v.y; o[2] = (__bf16)v.z; o[3] = (__bf16)v.w;
  *(bf4v*)(dst + off) = o;                         // one 8B store, fully packed
}

// ---------------- Delta operator: 3-pass chunked affine scan ----------------
__global__ __launch_bounds__(256) void delta_passA(const float* __restrict__ x,
                                                   const float* __restrict__ decay,
                                                   float* __restrict__ SA) {
  int idx = blockIdx.x * 256 + threadIdx.x;      // [b][c][d]
  int d = idx % DDIM;
  int c = (idx / DDIM) % NCH;
  int b = idx / (DDIM * NCH);
  float beta = sigm(decay[d]);
  float omb = 1.0f - beta;
  const float* xp = x + ((size_t)(b * SS + c * CLEN)) * DDIM + d;
  float s = 0.0f;
  for (int j = 0; j < CLEN; j++) {
    float xv = xp[(size_t)j * DDIM];
    s = beta * s + omb * xv;
  }
  SA[idx] = s;
}

__global__ __launch_bounds__(256) void delta_passB(const float* __restrict__ SA,
                                                   const float* __restrict__ decay,
                                                   float* __restrict__ SIN) {
  int idx = blockIdx.x * 256 + threadIdx.x;      // [b][d]
  int d = idx % DDIM;
  int b = idx / DDIM;
  float beta = sigm(decay[d]);
  float p = beta;
  for (int i = 0; i < 7; i++) p *= p;            // beta^128
  float s = 0.0f;
  for (int c = 0; c < NCH; c++) {
    SIN[(b * NCH + c) * DDIM + d] = s;
    s = p * s + SA[(b * NCH + c) * DDIM + d];
  }
}

__global__ __launch_bounds__(256) void delta_passC(const float* __restrict__ x,
                                                   const float* __restrict__ decay,
                                                   const float* __restrict__ SIN,
                                                   float* __restrict__ XD,
                                                   float* __restrict__ SA) {
  int idx = blockIdx.x * 256 + threadIdx.x;      // [b][c][d]
  int d = idx % DDIM;
  int c = (idx / DDIM) % NCH;
  int b = idx / (DDIM * NCH);
  float beta = sigm(decay[d]);
  float omb = 1.0f - beta;
  const float* xp = x + ((size_t)(b * SS + c * CLEN)) * DDIM + d;
  float* xdp = XD + ((size_t)(b * SS + c * CLEN)) * DDIM + d;
  float s = SIN[idx];
  float sum = 0.0f;
  for (int j = 0; j < CLEN; j++) {
    float xv = xp[(size_t)j * DDIM];
    float o = xv - s;
    xdp[(size_t)j * DDIM] = o;
    sum += o;
    s = beta * s + omb * xv;
  }
  SA[idx] = sum;
}

// ---------------- gates (g_res) + sinkhorn ----------------
__global__ __launch_bounds__(1024) void gates_sinkhorn(const float* __restrict__ SA,
                                                       const float* __restrict__ gw,
                                                       const float* __restrict__ gb,
                                                       const float* __restrict__ phi,
                                                       float* __restrict__ gres,
                                                       float* __restrict__ hres) {
  int tid = threadIdx.x;
  int wave = tid >> 6, lane = tid & 63;
  int b = wave >> 3, j = wave & 7;               // 16 waves: (b, gate j)
  float acc = 0.0f;
  for (int d = lane; d < DDIM; d += 64) {
    float xs = 0.0f;
    for (int c = 0; c < NCH; c++) xs += SA[(b * NCH + c) * DDIM + d];
    xs *= (1.0f / (float)SS);
    acc += xs * gw[(2 * NSTR + j) * DDIM + d];
  }
  for (int off = 32; off > 0; off >>= 1) acc += __shfl_down(acc, off);
  if (lane == 0) gres[b * NSTR + j] = sigm(acc + gb[2 * NSTR + j]);
  __syncthreads();
  if (tid == 0) {
    float Km[8][8];
    for (int i = 0; i < 8; i++)
      for (int jj = 0; jj < 8; jj++) Km[i][jj] = expf(phi[i * 8 + jj]);
    for (int it = 0; it < 15; it++) {
      for (int i = 0; i < 8; i++) {
        float rs = 0.0f;
        for (int jj = 0; jj < 8; jj++) rs += Km[i][jj];
        float inv = 1.0f / rs;
        for (int jj = 0; jj < 8; jj++) Km[i][jj] *= inv;
      }
      for (int jj = 0; jj < 8; jj++) {
        float cs = 0.0f;
        for (int i = 0; i < 8; i++) cs += Km[i][jj];
        float inv = 1.0f / cs;
        for (int i = 0; i < 8; i++) Km[i][jj] *= inv;
      }
    }
    for (int i = 0; i < 8; i++)
      for (int jj = 0; jj < 8; jj++) hres[i * 8 + jj] = Km[i][jj];
  }
}

// ---------------- RMSNorm (f32 in -> bf16 out) ----------------
__global__ __launch_bounds__(256) void rmsnorm_k(const float* __restrict__ in,
                                                 const float* __restrict__ w,
                                                 bf16* __restrict__ out) {
  int row = blockIdx.x;
  const float* r = in + (size_t)row * DDIM;
  int tid = threadIdx.x;
  float ss = 0.0f;
  for (int i = tid; i < DDIM; i += 256) {
    float v = r[i];
    ss += v * v;
  }
  for (int off = 32; off > 0; off >>= 1) ss += __shfl_down(ss, off);
  __shared__ float red[4];
  if ((tid & 63) == 0) red[tid >> 6] = ss;
  __syncthreads();
  float tot = red[0] + red[1] + red[2] + red[3];
  float sc = rsqrtf(tot / (float)DDIM + EPSV);
  bf16* o = out + (size_t)row * DDIM;
  for (int i = tid; i < DDIM; i += 256) o[i] = f2b(r[i] * sc * w[i]);
}

// ======================= gemm256: 256x256 / BK=64 / 8-wave 8-phase ==========
// T2 st_16x32 swizzle + T3 phase interleave + T4 counted vmcnt + T5 setprio.
// (validated round 5; see header comments there for the ledger)
// EPI: 0 = bf16 out (+bias), 1 = bf16 out gelu(x+bias)
template <int EPI>
__global__ __launch_bounds__(512, 2) void gemm256(const bf16* __restrict__ Ag,
                                                  const bf16* __restrict__ Wg,
                                                  const float* __restrict__ bias,
                                                  bf16* __restrict__ outp,
                                                  int M, int N, int K, int nby) {
  __shared__ __align__(16) bf16 As[2][16384];   // 2 x 32KB
  __shared__ __align__(16) bf16 Bs[2][16384];   // 2 x 32KB  (total 128KB)
  int nwg = gridDim.x;
  int cpx = nwg >> 3;                            // nwg % 8 == 0 (bijective T1)
  int l = (blockIdx.x & 7) * cpx + (blockIdx.x >> 3);
  int bm = l / nby, bn = l % nby;                // row-major: XCD keeps A-panel
  int m0 = bm * 256, n0 = bn * 256;
  int tid = threadIdx.x;
  int lane = tid & 63, wv = tid >> 6;
  int ml = lane & 15, quad = lane >> 4;
  int wrow = wv >> 2, wcol = wv & 3;             // 2x4 wave grid, 128x64 /wave

  size_t aoff[2][2], boff[2][2];
  int lof[2][2];
#pragma unroll
  for (int h = 0; h < 2; h++)
#pragma unroll
    for (int j = 0; j < 2; j++) {
      int b = tid * 16 + j * 8192;
      int s = b >> 10, w = b & 1023;
      int wl = w ^ (((w >> 9) & 1) << 5);
      int row = h * 128 + (s >> 1) * 16 + (wl >> 6);
      int col = (s & 1) * 32 + ((wl & 63) >> 1);
      aoff[h][j] = (size_t)(m0 + row) * K + col;
      boff[h][j] = (size_t)(n0 + row) * K + col;
      lof[h][j] = (h * 16384 + b) >> 1;
    }
  int wq2 = ((((ml << 6) + (quad << 4)) ^ (((int)(ml >= 8)) << 5))) >> 1;

#define SA_(c, kt, h) { glds16(&As[c][lof[h][0]], Ag + aoff[h][0] + (size_t)(kt) * 64); \
                        glds16(&As[c][lof[h][1]], Ag + aoff[h][1] + (size_t)(kt) * 64); }
#define SB_(c, kt, h) { glds16(&Bs[c][lof[h][0]], Wg + boff[h][0] + (size_t)(kt) * 64); \
                        glds16(&Bs[c][lof[h][1]], Wg + boff[h][1] + (size_t)(kt) * 64); }

  SA_(0, 0, 0); SA_(0, 0, 1);
  SB_(0, 0, 0); SB_(0, 0, 1);
  SB_(1, 1, 0); SB_(1, 1, 1);
  f4 acc[8][4] = {};
  asm volatile("s_waitcnt vmcnt(4)" ::: "memory");
  __builtin_amdgcn_s_barrier();
  asm volatile("" ::: "memory");

  int T = K >> 6;
  for (int t = 0; t < T; t++) {
    int c = t & 1;
    bf8 bfrag[4][2];
#pragma unroll
    for (int q = 0; q < 4; q++) {
      bf8 af[2][2];
#pragma unroll
      for (int mi2 = 0; mi2 < 2; mi2++)
#pragma unroll
        for (int kk = 0; kk < 2; kk++)
          af[mi2][kk] =
              ld8(&As[c][(((wrow * 8 + q * 2 + mi2) * 2 + kk) << 9) + wq2]);
      if (q == 0) {
#pragma unroll
        for (int ni = 0; ni < 4; ni++)
#pragma unroll
          for (int kk = 0; kk < 2; kk++)
            bfrag[ni][kk] =
                ld8(&Bs[c][(((wcol * 4 + ni) * 2 + kk) << 9) + wq2]);
      }
      if (q == 0 && t + 1 < T) SA_(c ^ 1, t + 1, 0);
      if (q == 1 && t + 1 < T) SA_(c ^ 1, t + 1, 1);
      if (q == 2 && t + 2 < T) SB_(c, t + 2, 0);
      if (q == 3 && t + 2 < T) SB_(c, t + 2, 1);
      __builtin_amdgcn_s_barrier();
      asm volatile("s_waitcnt lgkmcnt(0)" ::: "memory");
      __builtin_amdgcn_s_setprio(1);
#pragma unroll
      for (int mi2 = 0; mi2 < 2; mi2++)
#pragma unroll
        for (int ni = 0; ni < 4; ni++)
#pragma unroll
          for (int kk = 0; kk < 2; kk++)
            acc[q * 2 + mi2][ni] =
                MFMA(af[mi2][kk], bfrag[ni][kk], acc[q * 2 + mi2][ni]);
      __builtin_amdgcn_s_setprio(0);
      if (q == 3) {
        if (t + 2 < T) {
          asm volatile("s_waitcnt vmcnt(4)" ::: "memory");
        } else if (t + 1 < T) {
          asm volatile("s_waitcnt vmcnt(0)" ::: "memory");
        }
      }
      __builtin_amdgcn_s_barrier();
      asm volatile("" ::: "memory");
    }
  }
#pragma unroll
  for (int mi = 0; mi < 8; mi++)
#pragma unroll
    for (int ni = 0; ni < 4; ni++)
#pragma unroll
      for (int r = 0; r < 4; r++) {
        int row = m0 + wrow * 128 + mi * 16 + quad * 4 + r;
        int col = n0 + wcol * 64 + ni * 16 + ml;
        float v = acc[mi][ni][r] + bias[col];
        if (EPI == 1) v = gelu_f(v);
        outp[(size_t)row * N + col] = f2b(v);
      }
#undef SA_
#undef SB_
}

// ============== gemm256sk: 8-phase 256^2 with split-K=4, bf16 partials ======
// Same schedule as gemm256; grid = 4 splits x (M/256)x(N/256) blocks. Split s
// covers K-rows [s*K, (s+1)*K) of LDK-stride matrices. Partial outputs bf16
// (error ~|P|*2^-9 ~ 1e-3, negligible vs bf16-input GEMM noise). XCD swizzle
// groups 2 XCDs per split (A-slice 16MB/2 XCDs + B-slice 2MB -> L2-friendly).
__global__ __launch_bounds__(512, 2) void gemm256sk(const bf16* __restrict__ Ag,
                                                    const bf16* __restrict__ Wg,
                                                    bf16* __restrict__ P01,
                                                    bf16* __restrict__ P23,
                                                    int M, int N, int K, int LDK,
                                                    int nby) {
  __shared__ __align__(16) bf16 As[2][16384];
  __shared__ __align__(16) bf16 Bs[2][16384];
  int nwg = gridDim.x;
  int cpx = nwg >> 3;
  int l = (blockIdx.x & 7) * cpx + (blockIdx.x >> 3);
  int nper = nwg >> 2;                           // blocks per K-split
  int sk = l / nper;
  int idx = l % nper;
  int bm = idx / nby, bn = idx % nby;
  int m0 = bm * 256, n0 = bn * 256;
  bf16* outp = (sk < 2) ? (P01 + (size_t)sk * M * N)
                        : (P23 + (size_t)(sk - 2) * M * N);
  int kbase = sk * K;
  int tid = threadIdx.x;
  int lane = tid & 63, wv = tid >> 6;
  int ml = lane & 15, quad = lane >> 4;
  int wrow = wv >> 2, wcol = wv & 3;

  size_t aoff[2][2], boff[2][2];
  int lof[2][2];
#pragma unroll
  for (int h = 0; h < 2; h++)
#pragma unroll
    for (int j = 0; j < 2; j++) {
      int b = tid * 16 + j * 8192;
      int s = b >> 10, w = b & 1023;
      int wl = w ^ (((w >> 9) & 1) << 5);
      int row = h * 128 + (s >> 1) * 16 + (wl >> 6);
      int col = (s & 1) * 32 + ((wl & 63) >> 1);
      aoff[h][j] = (size_t)(m0 + row) * LDK + kbase + col;
      boff[h][j] = (size_t)(n0 + row) * LDK + kbase + col;
      lof[h][j] = (h * 16384 + b) >> 1;
    }
  int wq2 = ((((ml << 6) + (quad << 4)) ^ (((int)(ml >= 8)) << 5))) >> 1;

#define SA_(c, kt, h) { glds16(&As[c][lof[h][0]], Ag + aoff[h][0] + (size_t)(kt) * 64); \
                        glds16(&As[c][lof[h][1]], Ag + aoff[h][1] + (size_t)(kt) * 64); }
#define SB_(c, kt, h) { glds16(&Bs[c][lof[h][0]], Wg + boff[h][0] + (size_t)(kt) * 64); \
                        glds16(&Bs[c][lof[h][1]], Wg + boff[h][1] + (size_t)(kt) * 64); }

  SA_(0, 0, 0); SA_(0, 0, 1);
  SB_(0, 0, 0); SB_(0, 0, 1);
  SB_(1, 1, 0); SB_(1, 1, 1);
  f4 acc[8][4] = {};
  asm volatile("s_waitcnt vmcnt(4)" ::: "memory");
  __builtin_amdgcn_s_barrier();
  asm volatile("" ::: "memory");

  int T = K >> 6;
  for (int t = 0; t < T; t++) {
    int c = t & 1;
    bf8 bfrag[4][2];
#pragma unroll
    for (int q = 0; q < 4; q++) {
      bf8 af[2][2];
#pragma unroll
      for (int mi2 = 0; mi2 < 2; mi2++)
#pragma unroll
        for (int kk = 0; kk < 2; kk++)
          af[mi2][kk] =
              ld8(&As[c][(((wrow * 8 + q * 2 + mi2) * 2 + kk) << 9) + wq2]);
      if (q == 0) {
#pragma unroll
        for (int ni = 0; ni < 4; ni++)
#pragma unroll
          for (int kk = 0; kk < 2; kk++)
            bfrag[ni][kk] =
                ld8(&Bs[c][(((wcol * 4 + ni) * 2 + kk) << 9) + wq2]);
      }
      if (q == 0 && t + 1 < T) SA_(c ^ 1, t + 1, 0);
      if (q == 1 && t + 1 < T) SA_(c ^ 1, t + 1, 1);
      if (q == 2 && t + 2 < T) SB_(c, t + 2, 0);
      if (q == 3 && t + 2 < T) SB_(c, t + 2, 1);
      __builtin_amdgcn_s_barrier();
      asm volatile("s_waitcnt lgkmcnt(0)" ::: "memory");
      __builtin_amdgcn_s_setprio(1);
#pragma unroll
      for (int mi2 = 0; mi2 < 2; mi2++)
#pragma unroll
        for (int ni = 0; ni < 4; ni++)
#pragma unroll
          for (int kk = 0; kk < 2; kk++)
            acc[q * 2 + mi2][ni] =
                MFMA(af[mi2][kk], bfrag[ni][kk], acc[q * 2 + mi2][ni]);
      __builtin_amdgcn_s_setprio(0);
      if (q == 3) {
        if (t + 2 < T) {
          asm volatile("s_waitcnt vmcnt(4)" ::: "memory");
        } else if (t + 1 < T) {
          asm volatile("s_waitcnt vmcnt(0)" ::: "memory");
        }
      }
      __builtin_amdgcn_s_barrier();
      asm volatile("" ::: "memory");
    }
  }
#pragma unroll
  for (int mi = 0; mi < 8; mi++)
#pragma unroll
    for (int ni = 0; ni < 4; ni++)
#pragma unroll
      for (int r = 0; r < 4; r++) {
        int row = m0 + wrow * 128 + mi * 16 + quad * 4 + r;
        int col = n0 + wcol * 64 + ni * 16 + ml;
        outp[(size_t)row * N + col] = f2b(acc[mi][ni][r]);
      }
#undef SA_
#undef SB_
}

// ------- MFMA GEMM, BM=64 x BN=128 variant, double-buffered (round-3 form) --
template <int ODT, int EPI>
__global__ __launch_bounds__(256) void gemm_lds64(const bf16* __restrict__ A,
                                                  const bf16* __restrict__ W,
                                                  const float* __restrict__ bias,
                                                  const float* __restrict__ res,
                                                  void* __restrict__ outp,
                                                  int M, int N, int K) {
  __shared__ bf16 As[2][64 * 32];
  __shared__ bf16 Bs[2][128 * 32];
  int tid = threadIdx.x;
  int lane = tid & 63, wv = tid >> 6;
  int ml = lane & 15, quad = lane >> 4;
  int wr = wv & 1, wc = wv >> 1;        // wave tile: 32 rows x 64 cols
  int m0 = blockIdx.x * 64, n0 = blockIdx.y * 128;
  const bf16* gaA;
  const bf16* gb[2];
  int lofA, lofs[2];
  {
    int c = tid;                        // A: 256 chunks
    int row = c >> 2, kc = (c & 3) * 8;
    gaA = A + (size_t)(m0 + row) * K + kc;
    lofA = c * 8;
  }
#pragma unroll
  for (int it = 0; it < 2; it++) {      // B: 512 chunks
    int c = it * 256 + tid;
    int row = c >> 2, kc = (c & 3) * 8;
    gb[it] = W + (size_t)(n0 + row) * K + kc;
    lofs[it] = c * 8;
  }
  glds16(&As[0][lofA], gaA);
#pragma unroll
  for (int it = 0; it < 2; it++) glds16(&Bs[0][lofs[it]], gb[it]);
  f4 acc[2][4] = {};
  int nk = K >> 5;
  int cur = 0;
  __syncthreads();
  for (int t = 0; t < nk; t++) {
    if (t + 1 < nk) {
      int ko = (t + 1) * 32;
      glds16(&As[cur ^ 1][lofA], gaA + ko);
#pragma unroll
      for (int it = 0; it < 2; it++) glds16(&Bs[cur ^ 1][lofs[it]], gb[it] + ko);
    }
    bf8 af[2], bfr[4];
#pragma unroll
    for (int mi = 0; mi < 2; mi++)
      af[mi] = ld8(&As[cur][(wr * 32 + mi * 16 + ml) * 32 + quad * 8]);
#pragma unroll
    for (int ni = 0; ni < 4; ni++)
      bfr[ni] = ld8(&Bs[cur][(wc * 64 + ni * 16 + ml) * 32 + quad * 8]);
#pragma unroll
    for (int mi = 0; mi < 2; mi++)
#pragma unroll
      for (int ni = 0; ni < 4; ni++)
        acc[mi][ni] = MFMA(af[mi], bfr[ni], acc[mi][ni]);
    __syncthreads();
    cur ^= 1;
  }
#pragma unroll
  for (int mi = 0; mi < 2; mi++)
#pragma unroll
    for (int ni = 0; ni < 4; ni++)
#pragma unroll
      for (int r = 0; r < 4; r++) {
        int row = m0 + wr * 32 + mi * 16 + quad * 4 + r;
        int col = n0 + wc * 64 + ni * 16 + ml;
        size_t idx = (size_t)row * N + col;
        float v = acc[mi][ni][r] + bias[col];
        if (EPI == 1) v = gelu_f(v);
        if (EPI == 2) v += res[idx];
        if (ODT == 1) ((bf16*)outp)[idx] = f2b(v);
        else ((float*)outp)[idx] = v;
      }
}

// ---------------- V transpose: VT[b,h,d,s] = qkv[b,s,2D + h*64 + d] --------
__global__ __launch_bounds__(256) void vtrans(const bf16* __restrict__ qkv,
                                              bf16* __restrict__ VT) {
  int bid = blockIdx.x;
  int st = bid % (SS / 64);
  int h = (bid / (SS / 64)) % NHEAD;
  int b = bid / ((SS / 64) * NHEAD);
  __shared__ bf16 tile[64][65];
  int s0 = st * 64;
  int tid = threadIdx.x;
  for (int it = 0; it < 16; it++) {
    int sl = it * 4 + (tid >> 6), dl = tid & 63;
    tile[sl][dl] = qkv[(size_t)(b * SS + s0 + sl) * (3 * DDIM) + 2 * DDIM + h * 64 + dl];
  }
  __syncthreads();
  for (int it = 0; it < 16; it++) {
    int dl = it * 4 + (tid >> 6), sl = tid & 63;
    VT[((size_t)(b * NHEAD + h) * 64 + dl) * SS + s0 + sl] = tile[sl][dl];
  }
}

// ---- Flash attention v11: v10 + T13 defer-max (skip O-rescale when max
// growth <= 8 in log2 domain; P bounded by 2^8, O/l share scale -> exact)
// + v_max3-fusible max tree. Wave-uniform branch: per-row state replicates
// across quads after the xor16/32 reduce, so __all is well-defined.
__device__ __forceinline__ void qk_softmax(bool active, int kt, int q0, int nkt,
                                           const bf8 kf[4][2], const bf8* qf,
                                           f4* oacc, float& m, float& l,
                                           bf8* pf, bf16 (*pl)[72],
                                           int ml, int quad, int k0) {
  if (!active) return;                   // block-uniform condition
  const float SC = 0.125f * 1.44269504089f;  // 1/sqrt(64) * log2(e)
  f4 s[4] = {{0,0,0,0},{0,0,0,0},{0,0,0,0},{0,0,0,0}};
  __builtin_amdgcn_s_setprio(1);
#pragma unroll
  for (int kk = 0; kk < 2; kk++)
#pragma unroll
    for (int c = 0; c < 4; c++)
      s[c] = MFMA(kf[c][kk], qf[kk], s[c]);   // S^T = K . Q^T
  __builtin_amdgcn_s_setprio(0);
  if (kt == nkt - 1) {                   // diagonal tile: causal mask
    int qi = q0 + ml;
#pragma unroll
    for (int c = 0; c < 4; c++)
#pragma unroll
      for (int r = 0; r < 4; r++)
        if (k0 + c * 16 + quad * 4 + r > qi) s[c][r] = -1e30f;
  }
  // in-lane max over 16 k-values (max3 tree), then 2-step quad reduce
  float mx = max3f(s[0][0], s[0][1], s[0][2]);
  mx = max3f(mx, s[0][3], s[1][0]);
  mx = max3f(mx, s[1][1], s[1][2]);
  mx = max3f(mx, s[1][3], s[2][0]);
  mx = max3f(mx, s[2][1], s[2][2]);
  mx = max3f(mx, s[2][3], s[3][0]);
  mx = max3f(mx, s[3][1], s[3][2]);
  mx = fmaxf(mx, s[3][3]);
  mx = fmaxf(mx, __shfl_xor(mx, 16));
  mx = fmaxf(mx, __shfl_xor(mx, 32));
  float mxs = mx * SC;
  float p[4][4];
  float rs = 0.0f;
  if (__all(mxs - m <= 8.0f)) {          // T13: keep old max, skip rescale
#pragma unroll
    for (int c = 0; c < 4; c++)
#pragma unroll
      for (int r = 0; r < 4; r++) {
        p[c][r] = fexp2(__builtin_fmaf(s[c][r], SC, -m));
        rs += p[c][r];
      }
    rs += __shfl_xor(rs, 16);
    rs += __shfl_xor(rs, 32);
    l += rs;
  } else {
    float mn = fmaxf(m, mxs);
    float alpha = fexp2(m - mn);
#pragma unroll
    for (int c = 0; c < 4; c++)
#pragma unroll
      for (int r = 0; r < 4; r++) {
        p[c][r] = fexp2(__builtin_fmaf(s[c][r], SC, -mn));
        rs += p[c][r];
      }
    rs += __shfl_xor(rs, 16);
    rs += __shfl_xor(rs, 32);
    l = l * alpha + rs;
    m = mn;
    // redistribute alpha (state row q=ml) to O-layout rows (q=quad*4+r)
    float alr[4];
#pragma unroll
    for (int r = 0; r < 4; r++) alr[r] = __shfl(alpha, quad * 4 + r);
#pragma unroll
    for (int c = 0; c < 4; c++)
#pragma unroll
      for (int r = 0; r < 4; r++) oacc[c][r] *= alr[r];
  }
  // P is lane-local: pack 4 bf16 per chunk, one b64 write each
#pragma unroll
  for (int c = 0; c < 4; c++) {
    bf4v w;
#pragma unroll
    for (int r = 0; r < 4; r++) w[r] = (__bf16)p[c][r];
    *(bf4v*)&pl[ml][c * 16 + quad * 4] = w;
  }
#pragma unroll
  for (int kk = 0; kk < 2; kk++) pf[kk] = ld8(&pl[ml][kk * 32 + quad * 8]);
}

__device__ __forceinline__ void pv_acc(bool active, const bf8* pf,
                                       const bf8 vf[4][2], f4* oacc) {
  if (!active) return;
  __builtin_amdgcn_s_setprio(1);
#pragma unroll
  for (int c = 0; c < 4; c++)
#pragma unroll
    for (int kk = 0; kk < 2; kk++)
      oacc[c] = MFMA(pf[kk], vf[c][kk], oacc[c]);
  __builtin_amdgcn_s_setprio(0);
}

__global__ __launch_bounds__(256) void flash_attn(const bf16* __restrict__ qkv,
                                                  const bf16* __restrict__ VT,
                                                  bf16* __restrict__ obuf) {
  // T1 XCD swizzle: each XCD owns 4 complete (b,h) groups -> K/V L2-resident
  int rb = blockIdx.x;
  int bid = (rb & 7) * 64 + (rb >> 3);
  // complementary blk pairing (pair sums to 49 tiles)
  int j = bid & 15;
  int blk = (j & 1) ? (15 - (j >> 1)) : (j >> 1);
  int h = (bid >> 4) & 15;
  int b = bid >> 8;
  int tid = threadIdx.x;
  int wv = tid >> 6, lane = tid & 63;
  int ml = lane & 15, quad = lane >> 4;
  int idx0 = blk * 4 + wv;              // phase-0 subtile (16 Q rows)
  int idx1 = 127 - idx0;                // phase-1 (antithetic)
  int q0a = idx0 * 16, q0b = idx1 * 16;
  int nkt0 = blk + 1;                   // block-uniform
  int nkt1 = 32 - blk;                  // block-uniform; nkt1 >= nkt0
  int maxn = nkt1;

  __shared__ __align__(16) bf16 Ks[2][64 * 64];
  __shared__ __align__(16) bf16 Vs[2][64 * 64];
  __shared__ __align__(16) bf16 plds[4][2][16][72];  // per-wave, per-phase
  bf16 (*plA)[72] = plds[wv][0];
  bf16 (*plB)[72] = plds[wv][1];

  bf8 qfa[2], qfb[2];
#pragma unroll
  for (int kk = 0; kk < 2; kk++) {
    qfa[kk] = ld8(qkv + (size_t)(b * SS + q0a + ml) * (3 * DDIM) + h * 64 + kk * 32 + quad * 8);
    qfb[kk] = ld8(qkv + (size_t)(b * SS + q0b + ml) * (3 * DDIM) + h * 64 + kk * 32 + quad * 8);
  }
  f4 oacca[4] = {{0,0,0,0},{0,0,0,0},{0,0,0,0},{0,0,0,0}};
  f4 oaccb[4] = {{0,0,0,0},{0,0,0,0},{0,0,0,0},{0,0,0,0}};
  float ma = -1e30f, la = 0.0f, mb = -1e30f, lb = 0.0f;

  const bf16* kglob = qkv + (size_t)b * SS * (3 * DDIM) + DDIM + h * 64;
  const bf16* vglob = VT + (size_t)(b * NHEAD + h) * 64 * SS;

  // prologue: stage tile 0 into buffer 0 (swizzled SOURCE, lane-linear dest)
#pragma unroll
  for (int it = 0; it < 2; it++) {
    int lam = it * 256 + tid;
    int row = lam >> 3;
    int ch = (lam & 7) ^ (row & 7);
    glds16(&Ks[0][lam * 8], kglob + (size_t)row * (3 * DDIM) + ch * 8);
    glds16(&Vs[0][lam * 8], vglob + (size_t)row * SS + ch * 8);
  }
  __syncthreads();
  int cur = 0;
  for (int kt = 0; kt < maxn; kt++) {
    int k0 = kt * 64;
    if (kt + 1 < maxn) {                // prefetch next K/V tile
      int k0n = (kt + 1) * 64;
#pragma unroll
      for (int it = 0; it < 2; it++) {
        int lam = it * 256 + tid;
        int row = lam >> 3;
        int ch = (lam & 7) ^ (row & 7);
        glds16(&Ks[cur ^ 1][lam * 8], kglob + (size_t)(k0n + row) * (3 * DDIM) + ch * 8);
        glds16(&Vs[cur ^ 1][lam * 8], vglob + (size_t)row * SS + k0n + ch * 8);
      }
    }
    bool act0 = kt < nkt0;              // block-uniform
    bf8 kf[4][2];
#pragma unroll
    for (int kk = 0; kk < 2; kk++)
#pragma unroll
      for (int c = 0; c < 4; c++) {
        int chunk = ((c * 16 + ml) << 3) + ((kk * 4 + quad) ^ (ml & 7));
        kf[c][kk] = ld8(&Ks[cur][chunk * 8]);
      }
    bf8 pfa[2], pfb[2];
    qk_softmax(act0, kt, q0a, nkt0, kf, qfa, oacca, ma, la, pfa, plA, ml, quad, k0);
    qk_softmax(true, kt, q0b, nkt1, kf, qfb, oaccb, mb, lb, pfb, plB, ml, quad, k0);
    bf8 vf[4][2];
#pragma unroll
    for (int kk = 0; kk < 2; kk++)
#pragma unroll
      for (int c = 0; c < 4; c++) {
        int chunk = ((c * 16 + ml) << 3) + ((kk * 4 + quad) ^ (ml & 7));
        vf[c][kk] = ld8(&Vs[cur][chunk * 8]);
      }
    pv_acc(act0, pfa, vf, oacca);
    pv_acc(true, pfb, vf, oaccb);
    __syncthreads();                    // vmcnt(0)+lgkmcnt(0)+barrier
    cur ^= 1;
  }
  // redistribute l (state row q=ml) to O-layout rows, then store
  float lna[4], lnb[4];
#pragma unroll
  for (int r = 0; r < 4; r++) {
    lna[r] = __shfl(la, quad * 4 + r);
    lnb[r] = __shfl(lb, quad * 4 + r);
  }
#pragma unroll
  for (int c = 0; c < 4; c++)
#pragma unroll
    for (int r = 0; r < 4; r++) {
      int rowa = q0a + quad * 4 + r;
      int rowb = q0b + quad * 4 + r;
      obuf[(size_t)(b * SS + rowa) * DDIM + h * 64 + c * 16 + ml] =
          f2b(oacca[c][r] / lna[r]);
      obuf[(size_t)(b * SS + rowb) * DDIM + h * 64 + c * 16 + ml] =
          f2b(oaccb[c][r] / lnb[r]);
    }
}

// -------- final: out = y + P0+P1+P2+P3 (bf16 partials) + b2 + mhc(XD) ------
__global__ __launch_bounds__(256) void final_k(const float* __restrict__ y,
                                               const bf16* __restrict__ P0,
                                               const bf16* __restrict__ P1,
                                               const bf16* __restrict__ P2,
                                               const bf16* __restrict__ P3,
                                               const float* __restrict__ bias,
                                               const float* __restrict__ xd,
                                               const float* __restrict__ hres,
                                               const float* __restrict__ gres,
                                               float* __restrict__ out) {
  int row = blockIdx.x;  // [B*S]
  int b = row / SS;
  int tid = threadIdx.x;
  __shared__ float cf[8][8];
  if (tid < 64) cf[tid >> 3][tid & 7] = hres[tid] * gres[b * NSTR + (tid & 7)];
  __syncthreads();
  int i4 = tid * 4;                     // 256 thr x 4 = 1024 elems, one pass
  int m = i4 >> 7, dd = i4 & 127;
  size_t base = (size_t)row * DDIM + i4;
  f4 vy = *(const f4*)(y + base);
  f4 vb = *(const f4*)(bias + i4);
  bf4v p0 = *(const bf4v*)(P0 + base);
  bf4v p1 = *(const bf4v*)(P1 + base);
  bf4v p2 = *(const bf4v*)(P2 + base);
  bf4v p3 = *(const bf4v*)(P3 + base);
  const float* xr = xd + (size_t)row * DDIM;
  float acc[4];
#pragma unroll
  for (int jj = 0; jj < 4; jj++)
    acc[jj] = vy[jj] + vb[jj] + (float)p0[jj] + (float)p1[jj] +
              (float)p2[jj] + (float)p3[jj];
#pragma unroll
  for (int n = 0; n < 8; n++) {
    f4 vx = *(const f4*)(xr + n * SDIMC + dd);
#pragma unroll
    for (int jj = 0; jj < 4; jj++) acc[jj] += cf[m][n] * vx[jj];
  }
  f4 vo = {acc[0], acc[1], acc[2], acc[3]};
  *(f4*)(out + base) = vo;
}

extern "C" void kernel_launch(void* const* d_in, const int* in_sizes, int n_in,
                              void* d_out, int out_size, void* d_ws, size_t ws_size,
                              hipStream_t stream) {
  const float* x     = (const float*)d_in[0];
  const float* decay = (const float*)d_in[3];
  const float* gw    = (const float*)d_in[4];
  const float* gb    = (const float*)d_in[5];
  const float* phi   = (const float*)d_in[6];
  const float* ln1   = (const float*)d_in[7];
  const float* ln2   = (const float*)d_in[8];
  const float* w1    = (const float*)d_in[9];
  const float* b1    = (const float*)d_in[10];
  const float* w2    = (const float*)d_in[11];
  const float* b2    = (const float*)d_in[12];
  const float* ipw   = (const float*)d_in[13];
  const float* ipb   = (const float*)d_in[14];
  const float* ow    = (const float*)d_in[15];
  const float* obs   = (const float*)d_in[16];
  float* out = (float*)d_out;

  // ---- workspace layout (105 MB total) ----
  const size_t MB = 1048576ull;
  char* wsp = (char*)d_ws;
  float* SA   = (float*)(wsp);                 // 128 KB  chunk states / sums
  float* SIN  = (float*)(wsp + 131072ull);     // 128 KB  incoming states
  float* GRES = (float*)(wsp + 262144ull);     // 64 B
  float* HRES = (float*)(wsp + 262208ull);     // 256 B
  float* XD   = (float*)(wsp + 1 * MB);        // 16 MB   x_delta (f32), live to end
  float* AO   = (float*)(wsp + 17 * MB);       // 16 MB   y = x_delta + attn_out
  bf16*  NORM = (bf16*)(wsp + 33 * MB);        // 8 MB    normed/normed2 (dead after ffn1)
  bf16*  OB   = (bf16*)(wsp + 41 * MB);        // 8 MB    attn out (dead after outproj)
  bf16*  QKV  = (bf16*)(wsp + 49 * MB);        // 24 MB   (dead after flash)
  bf16*  VT   = (bf16*)(wsp + 73 * MB);        // 8 MB    (dead after flash)
  bf16*  HB   = (bf16*)(wsp + 49 * MB);        // 32 MB   gelu hidden, ALIASES QKV+VT
  bf16*  WIPW = (bf16*)(wsp + 81 * MB);        // 6 MB    in_proj_w bf16 (dead after qkv)
  bf16*  WOW  = (bf16*)(wsp + 87 * MB);        // 2 MB    out_w bf16 (dead after outproj)
  bf16*  W1B  = (bf16*)(wsp + 89 * MB);        // 8 MB    w1 bf16 (dead after ffn1)
  bf16*  W2B  = (bf16*)(wsp + 97 * MB);        // 8 MB    w2 bf16 (live thru ffn2)
  // ffn2 split-K=4 bf16 partials (8 MB each), live ffn2 -> final_k, over
  // dead regions: s0,s1 @ 33-49 (NORM+OB), s2,s3 @ 81-97 (WIPW/WOW/W1B)
  bf16* PKB0 = (bf16*)(wsp + 33 * MB);
  bf16* PKB2 = (bf16*)(wsp + 81 * MB);

  // 0: convert all GEMM weights f32 -> bf16
  cvt_all<<<dim3(12 * DDIM * DDIM / 1024), dim3(256), 0, stream>>>(
      ipw, ow, w1, w2, WIPW, WOW, W1B, W2B);

  // 1-3: delta operator scan
  delta_passA<<<dim3(BB * NCH * DDIM / 256), dim3(256), 0, stream>>>(x, decay, SA);
  delta_passB<<<dim3(BB * DDIM / 256), dim3(256), 0, stream>>>(SA, decay, SIN);
  delta_passC<<<dim3(BB * NCH * DDIM / 256), dim3(256), 0, stream>>>(x, decay, SIN, XD, SA);
  // 4: gates + sinkhorn
  gates_sinkhorn<<<dim3(1), dim3(1024), 0, stream>>>(SA, gw, gb, phi, GRES, HRES);
  // 5: rmsnorm1 (XD -> NORM)
  rmsnorm_k<<<dim3(BB * SS), dim3(256), 0, stream>>>(XD, ln1, NORM);
  // 6: qkv = NORM @ in_proj_w.T + in_proj_b   [4096 x 3072] -- 8-phase 256^2
  gemm256<0><<<dim3(192), dim3(512), 0, stream>>>(NORM, WIPW, ipb, QKV,
                                                  BB * SS, 3 * DDIM, DDIM, 12);
  // 7: V transpose
  vtrans<<<dim3(BB * NHEAD * (SS / 64)), dim3(256), 0, stream>>>(QKV, VT);
  // 8: flash attention -> OB (swapped QK^T + defer-max + max3)
  flash_attn<<<dim3(BB * NHEAD * 16), dim3(256), 0, stream>>>(QKV, VT, OB);
  // 9: out-proj + residual(XD) -> AO (= y)
  gemm_lds64<0, 2><<<dim3(64, 8), dim3(256), 0, stream>>>(OB, WOW, obs, XD,
                                                          AO, BB * SS, DDIM, DDIM);
  // 10: rmsnorm2 (AO -> NORM)
  rmsnorm_k<<<dim3(BB * SS), dim3(256), 0, stream>>>(AO, ln2, NORM);
  // 11: ffn1 + gelu -> HB   [4096 x 4096] -- 8-phase 256^2
  gemm256<1><<<dim3(256), dim3(512), 0, stream>>>(NORM, W1B, b1, HB,
                                                  BB * SS, 4 * DDIM, DDIM, 16);
  // 12: ffn2 split-K=4, 8-phase 256^2, bf16 partials (256 blocks, full chip)
  gemm256sk<<<dim3(256), dim3(512), 0, stream>>>(HB, W2B, PKB0, PKB2,
                                                 BB * SS, DDIM, DDIM, 4 * DDIM, 4);
  // 13: final out = y + sum(partials) + b2 + mhc(XD)   (vectorized)
  final_k<<<dim3(BB * SS), dim3(256), 0, stream>>>(
      AO, PKB0, PKB0 + (size_t)BB * SS * DDIM, PKB2,
      PKB2 + (size_t)BB * SS * DDIM, b2, XD, HRES, GRES, out);
}